// Round 4
// baseline (488.669 us; speedup 1.0000x reference)
//
#include <hip/hip_runtime.h>
#include <stdint.h>

// Problem constants
#define B_   2
#define S_   2048
#define D_   2048
#define NH_  16
#define DH_  128
#define N3_  6144

typedef unsigned short u16;
typedef __bf16 bf16x8 __attribute__((ext_vector_type(8)));
typedef float  f32x4  __attribute__((ext_vector_type(4)));

#define QSCALE   (0.08838834764831845f * 1.4426950408889634f)  // 1/sqrt(128) * log2(e)
#define BIASF    (-10000.0f * 1.4426950408889634f)

__device__ __forceinline__ u16 f2bf(float f) {
  union { float f; unsigned u; } v; v.f = f;
  unsigned u = v.u;
  return (u16)((u + 0x7FFFu + ((u >> 16) & 1u)) >> 16);
}

__device__ __forceinline__ float fast_exp2(float x) {
  float r;
  asm("v_exp_f32 %0, %1" : "=v"(r) : "v"(x));
  return r;
}

// async global->LDS, 16B per lane; LDS dest must be wave-uniform-base + lane*16
#define GL2LDS(gsrc, ldst)                                                              \
  __builtin_amdgcn_global_load_lds((const __attribute__((address_space(1))) void*)(gsrc), \
      (__attribute__((address_space(3))) void*)(ldst), 16, 0, 0)

// XCD-aware block swizzle: contiguous logical chunk per XCD. Requires total%8==0.
__device__ __forceinline__ int swz_id() {
  int id = blockIdx.y * gridDim.x + blockIdx.x;
  int cpx = (gridDim.x * gridDim.y) >> 3;
  return (id & 7) * cpx + (id >> 3);
}

// ---------------- fp32 -> bf16 convert (vectorized) ----------------
__global__ void cvt_kernel(const float* __restrict__ in, u16* __restrict__ out, int n4) {
  int i = blockIdx.x * blockDim.x + threadIdx.x;
  int stride = gridDim.x * blockDim.x;
  for (; i < n4; i += stride) {
    float4 v = ((const float4*)in)[i];
    ushort4 o;
    o.x = f2bf(v.x); o.y = f2bf(v.y); o.z = f2bf(v.z); o.w = f2bf(v.w);
    ((ushort4*)out)[i] = o;
  }
}

// ---------------- fp32 [K][N] -> bf16 [N][K] transpose ----------------
__global__ void transpose_kernel(const float* __restrict__ in, u16* __restrict__ out,
                                 int K, int N) {
  __shared__ float tile[32][33];
  int tx = threadIdx.x, ty = threadIdx.y;
  int nx = blockIdx.x * 32, ky = blockIdx.y * 32;
#pragma unroll
  for (int j = 0; j < 32; j += 8)
    tile[ty + j][tx] = in[(size_t)(ky + ty + j) * N + nx + tx];
  __syncthreads();
#pragma unroll
  for (int j = 0; j < 32; j += 8)
    out[(size_t)(nx + ty + j) * K + ky + tx] = f2bf(tile[tx][ty + j]);
}

// ================= 256x256 8-phase GEMM template (m201-style, re-derived) =========
// 512 threads = 8 waves (2M x 4N), per-wave 128x64 output, BK=64, LDS 128KiB.
// A-tile [256][64] stored as 2 "halves" by msub: half h = rows with (row>>6)&1==h,
// LDS half-row hr -> tile row (hr>>6)*128 + h*64 + (hr&63). B likewise by nsub:
// half h = B-rows (n) with (n>>5)&1==h, hbr -> n = (hbr>>5)*64 + h*32 + (hbr&31).
// Quadrant Q(ms,ns) reads exactly A-half ms + B-half ns.
// Per K-tile T (buf c=T&1), 4 phases:
//  ph1: [reads Q2 -> set1][bar][lgkm0][MFMA Q1 set0][bar]
//  ph2: [reads Q3 -> set0][stage Bh0(T+2)][bar][lgkm0][MFMA Q2 set1][bar]
//  ph3: [reads Q4 -> set1][stage Ah0(T+2)][bar][lgkm0][MFMA Q3 set0][bar]
//  ph4: [vmcnt(2)][stage Ah1,Bh1(T+2)][bar][reads Q1(T+1) -> set0][lgkm0][MFMA Q4 set1][bar]
// Retirement proof: half X of tile T is last READ (and lgkm-drained, barrier-
// separated) one phase before its restage for T+2. Gate proof: vmcnt(2)+bar at
// ph4 certifies (cross-wave) everything except the newest half-tile has landed;
// every read is issued after a gate+bar that covers its data.
// ==================================================================================

__device__ __forceinline__ void read_q(const u16* __restrict__ Ab, const u16* __restrict__ Bb,
                                       int wrB, int wcB, int g, int lr,
                                       bf16x8 (&AF)[4][2], bf16x8 (&BF)[2][2]) {
#pragma unroll
  for (int i = 0; i < 4; ++i) {
    int hr = wrB + i * 16 + lr;
#pragma unroll
    for (int kk = 0; kk < 2; ++kk)
      AF[i][kk] = *reinterpret_cast<const bf16x8*>(Ab + hr * 64 + ((((kk << 2) | g) ^ (hr & 7)) * 8));
  }
#pragma unroll
  for (int j = 0; j < 2; ++j) {
    int hbr = wcB + j * 16 + lr;
#pragma unroll
    for (int kk = 0; kk < 2; ++kk)
      BF[j][kk] = *reinterpret_cast<const bf16x8*>(Bb + hbr * 64 + ((((kk << 2) | g) ^ (hbr & 7)) * 8));
  }
}

template <int MS, int NS>
__device__ __forceinline__ void mfma_q(const bf16x8 (&AF)[4][2], const bf16x8 (&BF)[2][2],
                                       f32x4 (&acc)[8][4]) {
  __builtin_amdgcn_s_setprio(1);
#pragma unroll
  for (int i = 0; i < 4; ++i)
#pragma unroll
    for (int j = 0; j < 2; ++j)
#pragma unroll
      for (int kk = 0; kk < 2; ++kk)
        acc[MS * 4 + i][NS * 2 + j] = __builtin_amdgcn_mfma_f32_16x16x32_bf16(
            AF[i][kk], BF[j][kk], acc[MS * 4 + i][NS * 2 + j], 0, 0, 0);
  __builtin_amdgcn_s_setprio(0);
}

template <int KD>
__device__ __forceinline__ void stage_a(const u16* __restrict__ A, u16* lds,
                                        int c, int h, int Tg, int m0, int t) {
#pragma unroll
  for (int inst = 0; inst < 2; ++inst) {
    int idx = inst * 512 + t, hr = idx >> 3, slot = idx & 7;
    int trow = ((hr >> 6) << 7) + h * 64 + (hr & 63);
    GL2LDS(A + (size_t)(m0 + trow) * KD + Tg * 64 + ((slot ^ (hr & 7)) * 8),
           lds + c * 32768 + h * 8192 + idx * 8);
  }
}

template <int KD>
__device__ __forceinline__ void stage_b(const u16* __restrict__ BT, u16* lds,
                                        int c, int h, int Tg, int n0, int t) {
#pragma unroll
  for (int inst = 0; inst < 2; ++inst) {
    int idx = inst * 512 + t, hr = idx >> 3, slot = idx & 7;
    int n = ((hr >> 5) << 6) + h * 32 + (hr & 31);
    GL2LDS(BT + (size_t)(n0 + n) * KD + Tg * 64 + ((slot ^ (hr & 7)) * 8),
           lds + c * 32768 + 16384 + h * 8192 + idx * 8);
  }
}

#define ABASE(c, h) (lds + (c) * 32768 + (h) * 8192)
#define BBASE(c, h) (lds + (c) * 32768 + 16384 + (h) * 8192)
#define VMCNT(n) asm volatile("s_waitcnt vmcnt(" #n ")" ::: "memory")
#define LGKM0                                            \
  do {                                                   \
    asm volatile("s_waitcnt lgkmcnt(0)" ::: "memory");   \
    __builtin_amdgcn_sched_barrier(0);                   \
  } while (0)
#define BAR __builtin_amdgcn_s_barrier()

template <int KD>
__device__ __forceinline__ void gemm256_core(const u16* __restrict__ A, const u16* __restrict__ BT,
                                             int m0, int n0, u16* lds, f32x4 (&acc)[8][4]) {
  const int NT = KD / 64;
  int t = threadIdx.x, wv = t >> 6, lane = t & 63;
  int g = lane >> 4, lr = lane & 15;
  int wrB = (wv >> 2) * 64, wcB = (wv & 3) * 32;
  bf16x8 af0[4][2], bf0[2][2], af1[4][2], bf1[2][2];

  // prologue: tiles 0,1 staged in steady-state order; gate; Q1(0) into set0
  stage_b<KD>(BT, lds, 0, 0, 0, n0, t);
  stage_a<KD>(A, lds, 0, 0, 0, m0, t);
  stage_a<KD>(A, lds, 0, 1, 0, m0, t);
  stage_b<KD>(BT, lds, 0, 1, 0, n0, t);
  stage_b<KD>(BT, lds, 1, 0, 1, n0, t);
  stage_a<KD>(A, lds, 1, 0, 1, m0, t);
  VMCNT(2);
  stage_a<KD>(A, lds, 1, 1, 1, m0, t);
  stage_b<KD>(BT, lds, 1, 1, 1, n0, t);
  BAR;
  read_q(ABASE(0, 0), BBASE(0, 0), wrB, wcB, g, lr, af0, bf0);
  LGKM0;

  for (int T = 0; T < NT; ++T) {
    int c = T & 1;
    // ph1
    read_q(ABASE(c, 1), BBASE(c, 0), wrB, wcB, g, lr, af1, bf1);  // Q2
    BAR; LGKM0;
    mfma_q<0, 0>(af0, bf0, acc);
    BAR;
    // ph2
    read_q(ABASE(c, 0), BBASE(c, 1), wrB, wcB, g, lr, af0, bf0);  // Q3
    if (T + 2 < NT) stage_b<KD>(BT, lds, c, 0, T + 2, n0, t);
    BAR; LGKM0;
    mfma_q<1, 0>(af1, bf1, acc);
    BAR;
    // ph3
    read_q(ABASE(c, 1), BBASE(c, 1), wrB, wcB, g, lr, af1, bf1);  // Q4
    if (T + 2 < NT) stage_a<KD>(A, lds, c, 0, T + 2, m0, t);
    BAR; LGKM0;
    mfma_q<0, 1>(af0, bf0, acc);
    BAR;
    // ph4
    if (T + 2 < NT) {
      VMCNT(2);
      stage_a<KD>(A, lds, c, 1, T + 2, m0, t);
      stage_b<KD>(BT, lds, c, 1, T + 2, n0, t);
    } else {
      VMCNT(0);
    }
    BAR;
    if (T + 1 < NT) read_q(ABASE(c ^ 1, 0), BBASE(c ^ 1, 0), wrB, wcB, g, lr, af0, bf0);  // Q1(T+1)
    LGKM0;
    mfma_q<1, 1>(af1, bf1, acc);
    BAR;
  }
}

// ---------------- GEMM1: H @ Wattn + b -> scatter Q (prescaled), K, V^T ----------------
__global__ __launch_bounds__(512, 1) void gemm_qkv_kernel(
    const u16* __restrict__ A, const u16* __restrict__ BT, const float* __restrict__ bias,
    u16* __restrict__ Qb, u16* __restrict__ Kb, u16* __restrict__ VTb) {
  __shared__ __attribute__((aligned(16))) u16 lds[65536];
  f32x4 acc[8][4] = {};
  int sw = swz_id();
  int n0 = (sw % gridDim.x) * 256, m0 = (sw / gridDim.x) * 256;
  gemm256_core<2048>(A, BT, m0, n0, lds, acc);
  int t = threadIdx.x, lane = t & 63, wv = t >> 6;
  int g = lane >> 4, lr = lane & 15, wr = wv >> 2, wc = wv & 3;
#pragma unroll
  for (int mi = 0; mi < 8; ++mi) {
    int rowbase = m0 + wr * 128 + mi * 16 + g * 4;
    int b = rowbase >> 11, s = rowbase & 2047;
#pragma unroll
    for (int nj = 0; nj < 4; ++nj) {
      int col = n0 + wc * 64 + nj * 16 + lr;
      float bv = bias[col];
      int sec = col >> 11;            // 0=Q 1=K 2=V
      int within = col & 2047;
      int h = within >> 7, d = within & 127;
      if (sec < 2) {
        float mult = (sec == 0) ? QSCALE : 1.0f;   // fold 1/sqrt(dh)*log2e into Q
        u16* dst = (sec == 0 ? Qb : Kb) + ((size_t)(b * NH_ + h) * S_ + s) * DH_ + d;
#pragma unroll
        for (int r = 0; r < 4; ++r) dst[(size_t)r * DH_] = f2bf((acc[mi][nj][r] + bv) * mult);
      } else {
        u16* dst = VTb + ((size_t)(b * NH_ + h) * DH_ + d) * S_ + s;  // V transposed
        ushort4 pk;
        pk.x = f2bf(acc[mi][nj][0] + bv); pk.y = f2bf(acc[mi][nj][1] + bv);
        pk.z = f2bf(acc[mi][nj][2] + bv); pk.w = f2bf(acc[mi][nj][3] + bv);
        *reinterpret_cast<ushort4*>(dst) = pk;
      }
    }
  }
}

// ---------------- GEMM2: AO @ Wproj + b -> fp32 out ----------------
__global__ __launch_bounds__(512, 1) void gemm_proj_kernel(
    const u16* __restrict__ A, const u16* __restrict__ BT, const float* __restrict__ bias,
    float* __restrict__ out) {
  __shared__ __attribute__((aligned(16))) u16 lds[65536];
  f32x4 acc[8][4] = {};
  int sw = swz_id();
  int n0 = (sw % gridDim.x) * 256, m0 = (sw / gridDim.x) * 256;
  gemm256_core<2048>(A, BT, m0, n0, lds, acc);
  int t = threadIdx.x, lane = t & 63, wv = t >> 6;
  int g = lane >> 4, lr = lane & 15, wr = wv >> 2, wc = wv & 3;
#pragma unroll
  for (int mi = 0; mi < 8; ++mi) {
    int rowbase = m0 + wr * 128 + mi * 16 + g * 4;
#pragma unroll
    for (int nj = 0; nj < 4; ++nj) {
      int col = n0 + wc * 64 + nj * 16 + lr;
      float bv = bias[col];
      float* dst = out + (size_t)rowbase * D_ + col;
#pragma unroll
      for (int r = 0; r < 4; ++r) dst[(size_t)r * D_] = acc[mi][nj][r] + bv;
    }
  }
}

// ---------------- flash attention: pipelined K/V double-buffer (unchanged) --------
__global__ __launch_bounds__(256) void attn_kernel(
    const u16* __restrict__ Qb, const u16* __restrict__ Kb, const u16* __restrict__ VTb,
    const float* __restrict__ mask, u16* __restrict__ AO) {
  __shared__ __attribute__((aligned(16))) u16 Ks[2][64 * 128];
  __shared__ __attribute__((aligned(16))) u16 Vs[2][128 * 64];
  __shared__ __attribute__((aligned(16))) u16 Ps[4][16 * 64];
  __shared__ float bias_lds[S_];

  int t = threadIdx.x, w = t >> 6, lane = t & 63;
  int g = lane >> 4, lr = lane & 15;
  int sw = swz_id();                 // group same-(b,h) blocks per XCD
  int qt = sw & 31, bh = sw >> 5;
  int b = bh >> 4;
  const u16* Qh = Qb + (size_t)bh * S_ * DH_;
  const u16* Kh = Kb + (size_t)bh * S_ * DH_;
  const u16* Vh = VTb + (size_t)bh * DH_ * S_;
  int q0 = qt * 64 + w * 16;

  for (int i = t; i < S_; i += 256)
    bias_lds[i] = (1.0f - mask[b * S_ + i]) * BIASF;

  bf16x8 aq[4];
#pragma unroll
  for (int kk = 0; kk < 4; ++kk)
    aq[kk] = *reinterpret_cast<const bf16x8*>(Qh + (size_t)(q0 + lr) * DH_ + kk * 32 + g * 8);

  f32x4 oacc[8] = {};
  float m_r[4], l_r[4];
#pragma unroll
  for (int r = 0; r < 4; ++r) { m_r[r] = -1e30f; l_r[r] = 0.f; }

  __syncthreads();

#define STAGE_KV(buf, s0base)                                                    \
  {                                                                              \
    _Pragma("unroll")                                                            \
    for (int i = 0; i < 4; ++i) {                                                \
      int idx = i * 256 + t;                                                     \
      int row = idx >> 4, slot = idx & 15;                                       \
      GL2LDS(Kh + (size_t)((s0base) + row) * DH_ + ((slot ^ (row & 7)) * 8),     \
             &Ks[buf][idx * 8]);                                                 \
    }                                                                            \
    _Pragma("unroll")                                                            \
    for (int i = 0; i < 4; ++i) {                                                \
      int idx = i * 256 + t;                                                     \
      int row = idx >> 3, slot = idx & 7;                                        \
      GL2LDS(Vh + (size_t)row * S_ + (s0base) + ((slot ^ (row & 7)) * 8),        \
             &Vs[buf][idx * 8]);                                                 \
    }                                                                            \
  }

  STAGE_KV(0, 0);
  const int NT = S_ / 64;
  for (int it = 0; it < NT; ++it) {
    int cur = it & 1;
    if (it + 1 < NT) {
      STAGE_KV(cur ^ 1, (it + 1) * 64);
      asm volatile("s_waitcnt vmcnt(8)" ::: "memory");
    } else {
      asm volatile("s_waitcnt vmcnt(0)" ::: "memory");
    }
    __builtin_amdgcn_s_barrier();
    __builtin_amdgcn_sched_barrier(0);

    f32x4 sacc[4] = {};
#pragma unroll
    for (int kk = 0; kk < 4; ++kk) {
#pragma unroll
      for (int n = 0; n < 4; ++n) {
        int c = lr + 16 * n;
        bf16x8 bk = *reinterpret_cast<const bf16x8*>(
            &Ks[cur][c * 128 + ((((kk << 2) | g) ^ (c & 7)) * 8)]);
        sacc[n] = __builtin_amdgcn_mfma_f32_16x16x32_bf16(aq[kk], bk, sacc[n], 0, 0, 0);
      }
    }

    int s0 = it * 64;
    float sv[4][4], mx[4];
#pragma unroll
    for (int r = 0; r < 4; ++r) {
#pragma unroll
      for (int n = 0; n < 4; ++n) sv[r][n] = sacc[n][r] + bias_lds[s0 + lr + 16 * n];
      float m2 = fmaxf(fmaxf(sv[r][0], sv[r][1]), fmaxf(sv[r][2], sv[r][3]));
#pragma unroll
      for (int off = 1; off < 16; off <<= 1) m2 = fmaxf(m2, __shfl_xor(m2, off));
      mx[r] = m2;
    }
    float gmax = fmaxf(fmaxf(mx[0] - m_r[0], mx[1] - m_r[1]),
                       fmaxf(mx[2] - m_r[2], mx[3] - m_r[3]));
    if (__any(gmax > 8.f)) {
#pragma unroll
      for (int r = 0; r < 4; ++r) {
        float mnew = fmaxf(m_r[r], mx[r]);
        float f = fast_exp2(m_r[r] - mnew);
        m_r[r] = mnew;
        l_r[r] *= f;
#pragma unroll
        for (int no = 0; no < 8; ++no) oacc[no][r] *= f;
      }
    }
#pragma unroll
    for (int r = 0; r < 4; ++r) {
      int prow = g * 4 + r;
#pragma unroll
      for (int n = 0; n < 4; ++n) {
        float p = fast_exp2(sv[r][n] - m_r[r]);
        l_r[r] += p;
        int col = lr + 16 * n;
        Ps[w][prow * 64 + ((((col >> 3) ^ (prow & 7)) << 3) + (col & 7))] = f2bf(p);
      }
    }

#pragma unroll
    for (int kk2 = 0; kk2 < 2; ++kk2) {
      bf16x8 ap = *reinterpret_cast<const bf16x8*>(
          &Ps[w][lr * 64 + ((((kk2 << 2) | g) ^ (lr & 7)) * 8)]);
#pragma unroll
      for (int no = 0; no < 8; ++no) {
        int d = lr + 16 * no;
        bf16x8 bv = *reinterpret_cast<const bf16x8*>(
            &Vs[cur][d * 64 + ((((kk2 << 2) | g) ^ (d & 7)) * 8)]);
        oacc[no] = __builtin_amdgcn_mfma_f32_16x16x32_bf16(ap, bv, oacc[no], 0, 0, 0);
      }
    }
    __builtin_amdgcn_sched_barrier(0);
    __builtin_amdgcn_s_barrier();
  }
#undef STAGE_KV

#pragma unroll
  for (int r = 0; r < 4; ++r) {
    float s = l_r[r];
#pragma unroll
    for (int off = 1; off < 16; off <<= 1) s += __shfl_xor(s, off);
    float inv = 1.0f / s;
    int qrow = q0 + g * 4 + r;
    int h = bh & 15;
    u16* dst = AO + ((size_t)(b * S_ + qrow)) * D_ + h * DH_;
#pragma unroll
    for (int no = 0; no < 8; ++no) dst[lr + 16 * no] = f2bf(oacc[no][r] * inv);
  }
}

extern "C" void kernel_launch(void* const* d_in, const int* in_sizes, int n_in,
                              void* d_out, int out_size, void* d_ws, size_t ws_size,
                              hipStream_t stream) {
  const float* h_in   = (const float*)d_in[0];
  const float* mask   = (const float*)d_in[1];
  const float* w_attn = (const float*)d_in[2];
  const float* b_attn = (const float*)d_in[3];
  const float* w_proj = (const float*)d_in[4];
  const float* b_proj = (const float*)d_in[5];
  float* out = (float*)d_out;

  char* ws = (char*)d_ws;
  u16* Hb  = (u16*)(ws);                       // 16 MiB: H bf16 [4096][2048]
  u16* W1T = (u16*)(ws + 16777216);            // 24 MiB: Wattn^T bf16 [6144][2048]
  u16* W2T = (u16*)(ws + 41943040);            //  8 MiB: Wproj^T bf16 [2048][2048]
  u16* Qb  = (u16*)(ws + 50331648);            // 16 MiB: Q (prescaled) [B][H][S][128]
  u16* Kb  = (u16*)(ws + 67108864);            // 16 MiB: K  [B][H][S][128]
  u16* VTb = (u16*)(ws + 83886080);            // 16 MiB: V^T [B][H][128][S]
  u16* AO  = Hb;  // reuse H region for attention output (H dead after gemm_qkv)

  cvt_kernel<<<2048, 256, 0, stream>>>(h_in, Hb, (B_ * S_ * D_) / 4);
  dim3 tb(32, 8);
  transpose_kernel<<<dim3(N3_ / 32, D_ / 32), tb, 0, stream>>>(w_attn, W1T, D_, N3_);
  transpose_kernel<<<dim3(D_ / 32, D_ / 32), tb, 0, stream>>>(w_proj, W2T, D_, D_);
  gemm_qkv_kernel<<<dim3(N3_ / 256, (B_ * S_) / 256), 512, 0, stream>>>(
      Hb, W1T, b_attn, Qb, Kb, VTb);
  attn_kernel<<<dim3(S_ / 64, B_ * NH_), 256, 0, stream>>>(Qb, Kb, VTb, mask, AO);
  gemm_proj_kernel<<<dim3(D_ / 256, (B_ * S_) / 256), 512, 0, stream>>>(AO, W2T, b_proj, out);
}

// Round 6
// 445.332 us; speedup vs baseline: 1.0973x; 1.0973x over previous
//
#include <hip/hip_runtime.h>
#include <stdint.h>

// Problem constants
#define B_   2
#define S_   2048
#define D_   2048
#define NH_  16
#define DH_  128
#define N3_  6144

typedef unsigned short u16;
typedef __bf16 bf16x8 __attribute__((ext_vector_type(8)));
typedef float  f32x4  __attribute__((ext_vector_type(4)));

#define QSCALE   (0.08838834764831845f * 1.4426950408889634f)  // 1/sqrt(128) * log2(e)
#define BIASF    (-10000.0f * 1.4426950408889634f)

__device__ __forceinline__ u16 f2bf(float f) {
  union { float f; unsigned u; } v; v.f = f;
  unsigned u = v.u;
  return (u16)((u + 0x7FFFu + ((u >> 16) & 1u)) >> 16);
}

__device__ __forceinline__ float fast_exp2(float x) {
  float r;
  asm("v_exp_f32 %0, %1" : "=v"(r) : "v"(x));
  return r;
}

// async global->LDS, 16B per lane; LDS dest must be wave-uniform-base + lane*16
#define GL2LDS(gsrc, ldst)                                                              \
  __builtin_amdgcn_global_load_lds((const __attribute__((address_space(1))) void*)(gsrc), \
      (__attribute__((address_space(3))) void*)(ldst), 16, 0, 0)

// XCD-aware block swizzle: contiguous logical chunk per XCD. Requires total%8==0.
__device__ __forceinline__ int swz_id() {
  int id = blockIdx.y * gridDim.x + blockIdx.x;
  int cpx = (gridDim.x * gridDim.y) >> 3;
  return (id & 7) * cpx + (id >> 3);
}

// ---------------- fp32 -> bf16 convert (vectorized) ----------------
__global__ void cvt_kernel(const float* __restrict__ in, u16* __restrict__ out, int n4) {
  int i = blockIdx.x * blockDim.x + threadIdx.x;
  int stride = gridDim.x * blockDim.x;
  for (; i < n4; i += stride) {
    float4 v = ((const float4*)in)[i];
    ushort4 o;
    o.x = f2bf(v.x); o.y = f2bf(v.y); o.z = f2bf(v.z); o.w = f2bf(v.w);
    ((ushort4*)out)[i] = o;
  }
}

// ---------------- fp32 [K][N] -> bf16 [N][K] transpose ----------------
__global__ void transpose_kernel(const float* __restrict__ in, u16* __restrict__ out,
                                 int K, int N) {
  __shared__ float tile[32][33];
  int tx = threadIdx.x, ty = threadIdx.y;
  int nx = blockIdx.x * 32, ky = blockIdx.y * 32;
#pragma unroll
  for (int j = 0; j < 32; j += 8)
    tile[ty + j][tx] = in[(size_t)(ky + ty + j) * N + nx + tx];
  __syncthreads();
#pragma unroll
  for (int j = 0; j < 32; j += 8)
    out[(size_t)(nx + ty + j) * K + ky + tx] = f2bf(tile[tx][ty + j]);
}

// ============ K-split pipelined GEMM core: BM=256 x BN=128, BK=64 ===============
// 512 threads = 8 waves (4M x 2N), per-wave 64x64, acc[4][4]. LDS 96KiB:
// per buffer c: A k-half h = [256 rows][k 32] as paired rows [128][64] (16KB),
// B k-half = [128 rows][32] as [64][64] (8KB). Paired layout: row r at
// pair pr=r>>1, 16B slot = ((r&1)*4+g)^(pr&7)  (8 slots of 8 elems; the XOR
// spreads frag reads 2-way per bank = free). Stage writes LDS linearly with the
// inverse permutation on the global source address (both-sides swizzle rule).
// Phase schedule, 2 phases/K-tile, 4 barriers/K-tile, single counted vmcnt gate:
//  ph_a(T): [read frags(T,k1)->set1][stage k0(T+2)->buf c][BAR][lgkm0][MFMA set0][BAR]
//  ph_b(T): [vmcnt(3|0)][stage k1(T+2)->buf c][BAR][read frags(T+1,k0)->set0]
//           [lgkm0][MFMA set1][BAR]
// Safety: every restage of a half follows a barrier that postdates all readers'
// own lgkm0 (prologue adds one extra BAR for T=0). Gate proof: at ph_b(T) the
// outstanding queue is [ph_b(T-1):3][ph_a(T):3]; vmcnt(3) drains ph_b(T-1) =>
// tile T+1 fully landed before any wave reads it (BAR after gate). When
// ph_a(T) staged nothing (T+2>=NT) the invariant breaks => vmcnt(0) tail.
// ================================================================================

#define KS_ABASE(c, h) (lds + (c) * 24576 + (h) * 8192)
#define KS_BBASE(c, h) (lds + (c) * 24576 + 16384 + (h) * 4096)
#define VMCNT(n) asm volatile("s_waitcnt vmcnt(" #n ")" ::: "memory")
#define LGKM0                                            \
  do {                                                   \
    asm volatile("s_waitcnt lgkmcnt(0)" ::: "memory");   \
    __builtin_amdgcn_sched_barrier(0);                   \
  } while (0)
#define BAR __builtin_amdgcn_s_barrier()

__device__ __forceinline__ void ks_read_set(const u16* __restrict__ Ab,
                                            const u16* __restrict__ Bb,
                                            int wrB, int wcB, int lr, int g,
                                            bf16x8 (&af)[4], bf16x8 (&bf)[4]) {
#pragma unroll
  for (int i = 0; i < 4; ++i) {
    int r = wrB + i * 16 + lr;
    int pr = r >> 1;
    int slot = (((r & 1) << 2) | g) ^ (pr & 7);
    af[i] = *reinterpret_cast<const bf16x8*>(Ab + pr * 64 + slot * 8);
  }
#pragma unroll
  for (int j = 0; j < 4; ++j) {
    int n = wcB + j * 16 + lr;
    int pn = n >> 1;
    int slot = (((n & 1) << 2) | g) ^ (pn & 7);
    bf[j] = *reinterpret_cast<const bf16x8*>(Bb + pn * 64 + slot * 8);
  }
}

__device__ __forceinline__ void ks_mfma(const bf16x8 (&af)[4], const bf16x8 (&bf)[4],
                                        f32x4 (&acc)[4][4]) {
  __builtin_amdgcn_s_setprio(1);
#pragma unroll
  for (int i = 0; i < 4; ++i)
#pragma unroll
    for (int j = 0; j < 4; ++j)
      acc[i][j] = __builtin_amdgcn_mfma_f32_16x16x32_bf16(af[i], bf[j], acc[i][j], 0, 0, 0);
  __builtin_amdgcn_s_setprio(0);
}

template <int KD>
__device__ __forceinline__ void ks_stage(const u16* __restrict__ A,
                                         const u16* __restrict__ BT, u16* lds,
                                         int c, int h, int Tg, int m0, int n0, int t) {
#pragma unroll
  for (int inst = 0; inst < 2; ++inst) {       // A-half: 256x32 = 16KB = 2 insts
    int idx = inst * 512 + t;
    int pr = idx >> 3, s = idx & 7, v = s ^ (pr & 7);
    int r = pr * 2 + (v >> 2), g = v & 3;
    GL2LDS(A + (size_t)(m0 + r) * KD + Tg * 64 + h * 32 + g * 8,
           KS_ABASE(c, h) + idx * 8);
  }
  {                                            // B-half: 128x32 = 8KB = 1 inst
    int idx = t;
    int pn = idx >> 3, s = idx & 7, v = s ^ (pn & 7);
    int n = pn * 2 + (v >> 2), g = v & 3;
    GL2LDS(BT + (size_t)(n0 + n) * KD + Tg * 64 + h * 32 + g * 8,
           KS_BBASE(c, h) + idx * 8);
  }
}

template <int KD>
__device__ __forceinline__ void gemm_ks_core(const u16* __restrict__ A,
                                             const u16* __restrict__ BT,
                                             int m0, int n0, u16* lds, f32x4 (&acc)[4][4]) {
  const int NT = KD / 64;
  int t = threadIdx.x, wv = t >> 6, lane = t & 63;
  int g = lane >> 4, lr = lane & 15;
  int wrB = (wv >> 1) * 64, wcB = (wv & 1) * 64;
  bf16x8 af0[4], bf0[4], af1[4], bf1[4];

  // prologue: tiles 0,1 (12 insts); gate T0; read set0=(T0,k0); drain; safety BAR
  ks_stage<KD>(A, BT, lds, 0, 0, 0, m0, n0, t);
  ks_stage<KD>(A, BT, lds, 0, 1, 0, m0, n0, t);
  ks_stage<KD>(A, BT, lds, 1, 0, 1, m0, n0, t);
  ks_stage<KD>(A, BT, lds, 1, 1, 1, m0, n0, t);
  VMCNT(6);
  BAR;
  ks_read_set(KS_ABASE(0, 0), KS_BBASE(0, 0), wrB, wcB, lr, g, af0, bf0);
  LGKM0;
  BAR;

  for (int T = 0; T < NT; ++T) {
    int c = T & 1;
    // ph_a
    ks_read_set(KS_ABASE(c, 1), KS_BBASE(c, 1), wrB, wcB, lr, g, af1, bf1);
    if (T + 2 < NT) ks_stage<KD>(A, BT, lds, c, 0, T + 2, m0, n0, t);
    BAR;
    LGKM0;
    ks_mfma(af0, bf0, acc);
    BAR;
    // ph_b
    if (T + 2 < NT) {
      VMCNT(3);
      ks_stage<KD>(A, BT, lds, c, 1, T + 2, m0, n0, t);
    } else {
      VMCNT(0);
    }
    BAR;
    if (T + 1 < NT)
      ks_read_set(KS_ABASE(c ^ 1, 0), KS_BBASE(c ^ 1, 0), wrB, wcB, lr, g, af0, bf0);
    LGKM0;
    ks_mfma(af1, bf1, acc);
    BAR;
  }
}

// ---------------- GEMM1: H @ Wattn + b -> scatter Q (prescaled), K, V^T ----------------
__global__ __launch_bounds__(512, 2) void gemm_qkv_kernel(
    const u16* __restrict__ A, const u16* __restrict__ BT, const float* __restrict__ bias,
    u16* __restrict__ Qb, u16* __restrict__ Kb, u16* __restrict__ VTb) {
  __shared__ __attribute__((aligned(16))) u16 lds[49152];
  f32x4 acc[4][4] = {};
  int sw = swz_id();
  int n0 = (sw % gridDim.x) * 128, m0 = (sw / gridDim.x) * 256;
  gemm_ks_core<2048>(A, BT, m0, n0, lds, acc);
  int t = threadIdx.x, lane = t & 63, wv = t >> 6;
  int g = lane >> 4, lr = lane & 15;
  int wrB = (wv >> 1) * 64, wcB = (wv & 1) * 64;
#pragma unroll
  for (int mi = 0; mi < 4; ++mi) {
    int rowbase = m0 + wrB + mi * 16 + g * 4;
    int b = rowbase >> 11, s = rowbase & 2047;
#pragma unroll
    for (int nj = 0; nj < 4; ++nj) {
      int col = n0 + wcB + nj * 16 + lr;
      float bv = bias[col];
      int sec = col >> 11;            // 0=Q 1=K 2=V
      int within = col & 2047;
      int h = within >> 7, d = within & 127;
      if (sec < 2) {
        float mult = (sec == 0) ? QSCALE : 1.0f;   // fold 1/sqrt(dh)*log2e into Q
        u16* dst = (sec == 0 ? Qb : Kb) + ((size_t)(b * NH_ + h) * S_ + s) * DH_ + d;
#pragma unroll
        for (int r = 0; r < 4; ++r) dst[(size_t)r * DH_] = f2bf((acc[mi][nj][r] + bv) * mult);
      } else {
        u16* dst = VTb + ((size_t)(b * NH_ + h) * DH_ + d) * S_ + s;  // V transposed
        ushort4 pk;
        pk.x = f2bf(acc[mi][nj][0] + bv); pk.y = f2bf(acc[mi][nj][1] + bv);
        pk.z = f2bf(acc[mi][nj][2] + bv); pk.w = f2bf(acc[mi][nj][3] + bv);
        *reinterpret_cast<ushort4*>(dst) = pk;
      }
    }
  }
}

// ---------------- GEMM2: AO @ Wproj + b -> fp32 out ----------------
__global__ __launch_bounds__(512, 2) void gemm_proj_kernel(
    const u16* __restrict__ A, const u16* __restrict__ BT, const float* __restrict__ bias,
    float* __restrict__ out) {
  __shared__ __attribute__((aligned(16))) u16 lds[49152];
  f32x4 acc[4][4] = {};
  int sw = swz_id();
  int n0 = (sw % gridDim.x) * 128, m0 = (sw / gridDim.x) * 256;
  gemm_ks_core<2048>(A, BT, m0, n0, lds, acc);
  int t = threadIdx.x, lane = t & 63, wv = t >> 6;
  int g = lane >> 4, lr = lane & 15;
  int wrB = (wv >> 1) * 64, wcB = (wv & 1) * 64;
#pragma unroll
  for (int mi = 0; mi < 4; ++mi) {
    int rowbase = m0 + wrB + mi * 16 + g * 4;
#pragma unroll
    for (int nj = 0; nj < 4; ++nj) {
      int col = n0 + wcB + nj * 16 + lr;
      float bv = bias[col];
      float* dst = out + (size_t)rowbase * D_ + col;
#pragma unroll
      for (int r = 0; r < 4; ++r) dst[(size_t)r * D_] = acc[mi][nj][r] + bv;
    }
  }
}

// ---------------- flash attention: pipelined K/V double-buffer (unchanged) --------
__global__ __launch_bounds__(256) void attn_kernel(
    const u16* __restrict__ Qb, const u16* __restrict__ Kb, const u16* __restrict__ VTb,
    const float* __restrict__ mask, u16* __restrict__ AO) {
  __shared__ __attribute__((aligned(16))) u16 Ks[2][64 * 128];
  __shared__ __attribute__((aligned(16))) u16 Vs[2][128 * 64];
  __shared__ __attribute__((aligned(16))) u16 Ps[4][16 * 64];
  __shared__ float bias_lds[S_];

  int t = threadIdx.x, w = t >> 6, lane = t & 63;
  int g = lane >> 4, lr = lane & 15;
  int sw = swz_id();                 // group same-(b,h) blocks per XCD
  int qt = sw & 31, bh = sw >> 5;
  int b = bh >> 4;
  const u16* Qh = Qb + (size_t)bh * S_ * DH_;
  const u16* Kh = Kb + (size_t)bh * S_ * DH_;
  const u16* Vh = VTb + (size_t)bh * DH_ * S_;
  int q0 = qt * 64 + w * 16;

  for (int i = t; i < S_; i += 256)
    bias_lds[i] = (1.0f - mask[b * S_ + i]) * BIASF;

  bf16x8 aq[4];
#pragma unroll
  for (int kk = 0; kk < 4; ++kk)
    aq[kk] = *reinterpret_cast<const bf16x8*>(Qh + (size_t)(q0 + lr) * DH_ + kk * 32 + g * 8);

  f32x4 oacc[8] = {};
  float m_r[4], l_r[4];
#pragma unroll
  for (int r = 0; r < 4; ++r) { m_r[r] = -1e30f; l_r[r] = 0.f; }

  __syncthreads();

#define STAGE_KV(buf, s0base)                                                    \
  {                                                                              \
    _Pragma("unroll")                                                            \
    for (int i = 0; i < 4; ++i) {                                                \
      int idx = i * 256 + t;                                                     \
      int row = idx >> 4, slot = idx & 15;                                       \
      GL2LDS(Kh + (size_t)((s0base) + row) * DH_ + ((slot ^ (row & 7)) * 8),     \
             &Ks[buf][idx * 8]);                                                 \
    }                                                                            \
    _Pragma("unroll")                                                            \
    for (int i = 0; i < 4; ++i) {                                                \
      int idx = i * 256 + t;                                                     \
      int row = idx >> 3, slot = idx & 7;                                        \
      GL2LDS(Vh + (size_t)row * S_ + (s0base) + ((slot ^ (row & 7)) * 8),        \
             &Vs[buf][idx * 8]);                                                 \
    }                                                                            \
  }

  STAGE_KV(0, 0);
  const int NT = S_ / 64;
  for (int it = 0; it < NT; ++it) {
    int cur = it & 1;
    if (it + 1 < NT) {
      STAGE_KV(cur ^ 1, (it + 1) * 64);
      asm volatile("s_waitcnt vmcnt(8)" ::: "memory");
    } else {
      asm volatile("s_waitcnt vmcnt(0)" ::: "memory");
    }
    __builtin_amdgcn_s_barrier();
    __builtin_amdgcn_sched_barrier(0);

    f32x4 sacc[4] = {};
#pragma unroll
    for (int kk = 0; kk < 4; ++kk) {
#pragma unroll
      for (int n = 0; n < 4; ++n) {
        int c = lr + 16 * n;
        bf16x8 bk = *reinterpret_cast<const bf16x8*>(
            &Ks[cur][c * 128 + ((((kk << 2) | g) ^ (c & 7)) * 8)]);
        sacc[n] = __builtin_amdgcn_mfma_f32_16x16x32_bf16(aq[kk], bk, sacc[n], 0, 0, 0);
      }
    }

    int s0 = it * 64;
    float sv[4][4], mx[4];
#pragma unroll
    for (int r = 0; r < 4; ++r) {
#pragma unroll
      for (int n = 0; n < 4; ++n) sv[r][n] = sacc[n][r] + bias_lds[s0 + lr + 16 * n];
      float m2 = fmaxf(fmaxf(sv[r][0], sv[r][1]), fmaxf(sv[r][2], sv[r][3]));
#pragma unroll
      for (int off = 1; off < 16; off <<= 1) m2 = fmaxf(m2, __shfl_xor(m2, off));
      mx[r] = m2;
    }
    float gmax = fmaxf(fmaxf(mx[0] - m_r[0], mx[1] - m_r[1]),
                       fmaxf(mx[2] - m_r[2], mx[3] - m_r[3]));
    if (__any(gmax > 8.f)) {
#pragma unroll
      for (int r = 0; r < 4; ++r) {
        float mnew = fmaxf(m_r[r], mx[r]);
        float f = fast_exp2(m_r[r] - mnew);
        m_r[r] = mnew;
        l_r[r] *= f;
#pragma unroll
        for (int no = 0; no < 8; ++no) oacc[no][r] *= f;
      }
    }
#pragma unroll
    for (int r = 0; r < 4; ++r) {
      int prow = g * 4 + r;
#pragma unroll
      for (int n = 0; n < 4; ++n) {
        float p = fast_exp2(sv[r][n] - m_r[r]);
        l_r[r] += p;
        int col = lr + 16 * n;
        Ps[w][prow * 64 + ((((col >> 3) ^ (prow & 7)) << 3) + (col & 7))] = f2bf(p);
      }
    }

#pragma unroll
    for (int kk2 = 0; kk2 < 2; ++kk2) {
      bf16x8 ap = *reinterpret_cast<const bf16x8*>(
          &Ps[w][lr * 64 + ((((kk2 << 2) | g) ^ (lr & 7)) * 8)]);
#pragma unroll
      for (int no = 0; no < 8; ++no) {
        int d = lr + 16 * no;
        bf16x8 bv = *reinterpret_cast<const bf16x8*>(
            &Vs[cur][d * 64 + ((((kk2 << 2) | g) ^ (d & 7)) * 8)]);
        oacc[no] = __builtin_amdgcn_mfma_f32_16x16x32_bf16(ap, bv, oacc[no], 0, 0, 0);
      }
    }
    __builtin_amdgcn_sched_barrier(0);
    __builtin_amdgcn_s_barrier();
  }
#undef STAGE_KV

#pragma unroll
  for (int r = 0; r < 4; ++r) {
    float s = l_r[r];
#pragma unroll
    for (int off = 1; off < 16; off <<= 1) s += __shfl_xor(s, off);
    float inv = 1.0f / s;
    int qrow = q0 + g * 4 + r;
    int h = bh & 15;
    u16* dst = AO + ((size_t)(b * S_ + qrow)) * D_ + h * DH_;
#pragma unroll
    for (int no = 0; no < 8; ++no) dst[lr + 16 * no] = f2bf(oacc[no][r] * inv);
  }
}

extern "C" void kernel_launch(void* const* d_in, const int* in_sizes, int n_in,
                              void* d_out, int out_size, void* d_ws, size_t ws_size,
                              hipStream_t stream) {
  const float* h_in   = (const float*)d_in[0];
  const float* mask   = (const float*)d_in[1];
  const float* w_attn = (const float*)d_in[2];
  const float* b_attn = (const float*)d_in[3];
  const float* w_proj = (const float*)d_in[4];
  const float* b_proj = (const float*)d_in[5];
  float* out = (float*)d_out;

  char* ws = (char*)d_ws;
  u16* Hb  = (u16*)(ws);                       // 16 MiB: H bf16 [4096][2048]
  u16* W1T = (u16*)(ws + 16777216);            // 24 MiB: Wattn^T bf16 [6144][2048]
  u16* W2T = (u16*)(ws + 41943040);            //  8 MiB: Wproj^T bf16 [2048][2048]
  u16* Qb  = (u16*)(ws + 50331648);            // 16 MiB: Q (prescaled) [B][H][S][128]
  u16* Kb  = (u16*)(ws + 67108864);            // 16 MiB: K  [B][H][S][128]
  u16* VTb = (u16*)(ws + 83886080);            // 16 MiB: V^T [B][H][128][S]
  u16* AO  = Hb;  // reuse H region for attention output (H dead after gemm_qkv)

  cvt_kernel<<<2048, 256, 0, stream>>>(h_in, Hb, (B_ * S_ * D_) / 4);
  dim3 tb(32, 8);
  transpose_kernel<<<dim3(N3_ / 32, D_ / 32), tb, 0, stream>>>(w_attn, W1T, D_, N3_);
  transpose_kernel<<<dim3(D_ / 32, D_ / 32), tb, 0, stream>>>(w_proj, W2T, D_, D_);
  gemm_qkv_kernel<<<dim3(N3_ / 128, (B_ * S_) / 256), 512, 0, stream>>>(
      Hb, W1T, b_attn, Qb, Kb, VTb);
  attn_kernel<<<dim3(S_ / 64, B_ * NH_), 256, 0, stream>>>(Qb, Kb, VTb, mask, AO);
  gemm_proj_kernel<<<dim3(D_ / 128, (B_ * S_) / 256), 512, 0, stream>>>(AO, W2T, b_proj, out);
}

// Round 7
// 434.706 us; speedup vs baseline: 1.1241x; 1.0244x over previous
//
#include <hip/hip_runtime.h>
#include <stdint.h>

// Problem constants
#define B_   2
#define S_   2048
#define D_   2048
#define NH_  16
#define DH_  128
#define N3_  6144

typedef unsigned short u16;
typedef __bf16 bf16x8 __attribute__((ext_vector_type(8)));
typedef float  f32x4  __attribute__((ext_vector_type(4)));

#define QSCALE   (0.08838834764831845f * 1.4426950408889634f)  // 1/sqrt(128) * log2(e)
#define BIASF    (-10000.0f * 1.4426950408889634f)

__device__ __forceinline__ u16 f2bf(float f) {
  union { float f; unsigned u; } v; v.f = f;
  unsigned u = v.u;
  return (u16)((u + 0x7FFFu + ((u >> 16) & 1u)) >> 16);
}

__device__ __forceinline__ float fast_exp2(float x) {
  float r;
  asm("v_exp_f32 %0, %1" : "=v"(r) : "v"(x));
  return r;
}

__device__ __forceinline__ unsigned cvtpk(float lo, float hi) {
  unsigned r;
  asm("v_cvt_pk_bf16_f32 %0, %1, %2" : "=v"(r) : "v"(lo), "v"(hi));
  return r;
}

// async global->LDS, 16B per lane; LDS dest must be wave-uniform-base + lane*16
#define GL2LDS(gsrc, ldst)                                                              \
  __builtin_amdgcn_global_load_lds((const __attribute__((address_space(1))) void*)(gsrc), \
      (__attribute__((address_space(3))) void*)(ldst), 16, 0, 0)

// XCD-aware block swizzle: contiguous logical chunk per XCD. Requires total%8==0.
__device__ __forceinline__ int swz_id() {
  int id = blockIdx.y * gridDim.x + blockIdx.x;
  int cpx = (gridDim.x * gridDim.y) >> 3;
  return (id & 7) * cpx + (id >> 3);
}

// ---------------- fp32 -> bf16 convert (vectorized) ----------------
__global__ void cvt_kernel(const float* __restrict__ in, u16* __restrict__ out, int n4) {
  int i = blockIdx.x * blockDim.x + threadIdx.x;
  int stride = gridDim.x * blockDim.x;
  for (; i < n4; i += stride) {
    float4 v = ((const float4*)in)[i];
    ushort4 o;
    o.x = f2bf(v.x); o.y = f2bf(v.y); o.z = f2bf(v.z); o.w = f2bf(v.w);
    ((ushort4*)out)[i] = o;
  }
}

// ---------------- fp32 [K][N] -> bf16 [N][K] transpose ----------------
__global__ void transpose_kernel(const float* __restrict__ in, u16* __restrict__ out,
                                 int K, int N) {
  __shared__ float tile[32][33];
  int tx = threadIdx.x, ty = threadIdx.y;
  int nx = blockIdx.x * 32, ky = blockIdx.y * 32;
#pragma unroll
  for (int j = 0; j < 32; j += 8)
    tile[ty + j][tx] = in[(size_t)(ky + ty + j) * N + nx + tx];
  __syncthreads();
#pragma unroll
  for (int j = 0; j < 32; j += 8)
    out[(size_t)(nx + ty + j) * K + ky + tx] = f2bf(tile[tx][ty + j]);
}

// ============ K-split pipelined GEMM core: BM=256 x BN=128, BK=64 ===============
// (structure unchanged from R4/R6 -- correctness-proven; launch_bounds fixed to
// (512,1): 96KiB LDS means only 1 block/CU fits anyway, and the old min-waves=2
// capped VGPR at 128 -> spills. Now allocator gets 256.)
// ================================================================================

#define KS_ABASE(c, h) (lds + (c) * 24576 + (h) * 8192)
#define KS_BBASE(c, h) (lds + (c) * 24576 + 16384 + (h) * 4096)
#define VMCNT(n) asm volatile("s_waitcnt vmcnt(" #n ")" ::: "memory")
#define LGKM0                                            \
  do {                                                   \
    asm volatile("s_waitcnt lgkmcnt(0)" ::: "memory");   \
    __builtin_amdgcn_sched_barrier(0);                   \
  } while (0)
#define BAR __builtin_amdgcn_s_barrier()

__device__ __forceinline__ void ks_read_set(const u16* __restrict__ Ab,
                                            const u16* __restrict__ Bb,
                                            int wrB, int wcB, int lr, int g,
                                            bf16x8 (&af)[4], bf16x8 (&bf)[4]) {
#pragma unroll
  for (int i = 0; i < 4; ++i) {
    int r = wrB + i * 16 + lr;
    int pr = r >> 1;
    int slot = (((r & 1) << 2) | g) ^ (pr & 7);
    af[i] = *reinterpret_cast<const bf16x8*>(Ab + pr * 64 + slot * 8);
  }
#pragma unroll
  for (int j = 0; j < 4; ++j) {
    int n = wcB + j * 16 + lr;
    int pn = n >> 1;
    int slot = (((n & 1) << 2) | g) ^ (pn & 7);
    bf[j] = *reinterpret_cast<const bf16x8*>(Bb + pn * 64 + slot * 8);
  }
}

__device__ __forceinline__ void ks_mfma(const bf16x8 (&af)[4], const bf16x8 (&bf)[4],
                                        f32x4 (&acc)[4][4]) {
  __builtin_amdgcn_s_setprio(1);
#pragma unroll
  for (int i = 0; i < 4; ++i)
#pragma unroll
    for (int j = 0; j < 4; ++j)
      acc[i][j] = __builtin_amdgcn_mfma_f32_16x16x32_bf16(af[i], bf[j], acc[i][j], 0, 0, 0);
  __builtin_amdgcn_s_setprio(0);
}

template <int KD>
__device__ __forceinline__ void ks_stage(const u16* __restrict__ A,
                                         const u16* __restrict__ BT, u16* lds,
                                         int c, int h, int Tg, int m0, int n0, int t) {
#pragma unroll
  for (int inst = 0; inst < 2; ++inst) {       // A-half: 256x32 = 16KB = 2 insts
    int idx = inst * 512 + t;
    int pr = idx >> 3, s = idx & 7, v = s ^ (pr & 7);
    int r = pr * 2 + (v >> 2), g = v & 3;
    GL2LDS(A + (size_t)(m0 + r) * KD + Tg * 64 + h * 32 + g * 8,
           KS_ABASE(c, h) + idx * 8);
  }
  {                                            // B-half: 128x32 = 8KB = 1 inst
    int idx = t;
    int pn = idx >> 3, s = idx & 7, v = s ^ (pn & 7);
    int n = pn * 2 + (v >> 2), g = v & 3;
    GL2LDS(BT + (size_t)(n0 + n) * KD + Tg * 64 + h * 32 + g * 8,
           KS_BBASE(c, h) + idx * 8);
  }
}

template <int KD>
__device__ __forceinline__ void gemm_ks_core(const u16* __restrict__ A,
                                             const u16* __restrict__ BT,
                                             int m0, int n0, u16* lds, f32x4 (&acc)[4][4]) {
  const int NT = KD / 64;
  int t = threadIdx.x, wv = t >> 6, lane = t & 63;
  int g = lane >> 4, lr = lane & 15;
  int wrB = (wv >> 1) * 64, wcB = (wv & 1) * 64;
  bf16x8 af0[4], bf0[4], af1[4], bf1[4];

  // prologue: tiles 0,1 (12 insts); gate T0; read set0=(T0,k0); drain; safety BAR
  ks_stage<KD>(A, BT, lds, 0, 0, 0, m0, n0, t);
  ks_stage<KD>(A, BT, lds, 0, 1, 0, m0, n0, t);
  ks_stage<KD>(A, BT, lds, 1, 0, 1, m0, n0, t);
  ks_stage<KD>(A, BT, lds, 1, 1, 1, m0, n0, t);
  VMCNT(6);
  BAR;
  ks_read_set(KS_ABASE(0, 0), KS_BBASE(0, 0), wrB, wcB, lr, g, af0, bf0);
  LGKM0;
  BAR;

  for (int T = 0; T < NT; ++T) {
    int c = T & 1;
    // ph_a
    ks_read_set(KS_ABASE(c, 1), KS_BBASE(c, 1), wrB, wcB, lr, g, af1, bf1);
    if (T + 2 < NT) ks_stage<KD>(A, BT, lds, c, 0, T + 2, m0, n0, t);
    BAR;
    LGKM0;
    ks_mfma(af0, bf0, acc);
    BAR;
    // ph_b
    if (T + 2 < NT) {
      VMCNT(3);
      ks_stage<KD>(A, BT, lds, c, 1, T + 2, m0, n0, t);
    } else {
      VMCNT(0);
    }
    BAR;
    if (T + 1 < NT)
      ks_read_set(KS_ABASE(c ^ 1, 0), KS_BBASE(c ^ 1, 0), wrB, wcB, lr, g, af0, bf0);
    LGKM0;
    ks_mfma(af1, bf1, acc);
    BAR;
  }
}

// ---------------- GEMM1: H @ Wattn + b -> scatter Q (prescaled), K, V^T ----------------
__global__ __launch_bounds__(512, 1) void gemm_qkv_kernel(
    const u16* __restrict__ A, const u16* __restrict__ BT, const float* __restrict__ bias,
    u16* __restrict__ Qb, u16* __restrict__ Kb, u16* __restrict__ VTb) {
  __shared__ __attribute__((aligned(16))) u16 lds[49152];
  f32x4 acc[4][4] = {};
  int sw = swz_id();
  int n0 = (sw % gridDim.x) * 128, m0 = (sw / gridDim.x) * 256;
  gemm_ks_core<2048>(A, BT, m0, n0, lds, acc);
  int t = threadIdx.x, lane = t & 63, wv = t >> 6;
  int g = lane >> 4, lr = lane & 15;
  int wrB = (wv >> 1) * 64, wcB = (wv & 1) * 64;
#pragma unroll
  for (int mi = 0; mi < 4; ++mi) {
    int rowbase = m0 + wrB + mi * 16 + g * 4;
    int b = rowbase >> 11, s = rowbase & 2047;
#pragma unroll
    for (int nj = 0; nj < 4; ++nj) {
      int col = n0 + wcB + nj * 16 + lr;
      float bv = bias[col];
      int sec = col >> 11;            // 0=Q 1=K 2=V
      int within = col & 2047;
      int h = within >> 7, d = within & 127;
      if (sec < 2) {
        float mult = (sec == 0) ? QSCALE : 1.0f;   // fold 1/sqrt(dh)*log2e into Q
        u16* dst = (sec == 0 ? Qb : Kb) + ((size_t)(b * NH_ + h) * S_ + s) * DH_ + d;
#pragma unroll
        for (int r = 0; r < 4; ++r) dst[(size_t)r * DH_] = f2bf((acc[mi][nj][r] + bv) * mult);
      } else {
        u16* dst = VTb + ((size_t)(b * NH_ + h) * DH_ + d) * S_ + s;  // V transposed
        ushort4 pk;
        pk.x = f2bf(acc[mi][nj][0] + bv); pk.y = f2bf(acc[mi][nj][1] + bv);
        pk.z = f2bf(acc[mi][nj][2] + bv); pk.w = f2bf(acc[mi][nj][3] + bv);
        *reinterpret_cast<ushort4*>(dst) = pk;
      }
    }
  }
}

// ---------------- GEMM2: AO @ Wproj + b -> fp32 out ----------------
__global__ __launch_bounds__(512, 1) void gemm_proj_kernel(
    const u16* __restrict__ A, const u16* __restrict__ BT, const float* __restrict__ bias,
    float* __restrict__ out) {
  __shared__ __attribute__((aligned(16))) u16 lds[49152];
  f32x4 acc[4][4] = {};
  int sw = swz_id();
  int n0 = (sw % gridDim.x) * 128, m0 = (sw / gridDim.x) * 256;
  gemm_ks_core<2048>(A, BT, m0, n0, lds, acc);
  int t = threadIdx.x, lane = t & 63, wv = t >> 6;
  int g = lane >> 4, lr = lane & 15;
  int wrB = (wv >> 1) * 64, wcB = (wv & 1) * 64;
#pragma unroll
  for (int mi = 0; mi < 4; ++mi) {
    int rowbase = m0 + wrB + mi * 16 + g * 4;
#pragma unroll
    for (int nj = 0; nj < 4; ++nj) {
      int col = n0 + wcB + nj * 16 + lr;
      float bv = bias[col];
      float* dst = out + (size_t)rowbase * D_ + col;
#pragma unroll
      for (int r = 0; r < 4; ++r) dst[(size_t)r * D_] = acc[mi][nj][r] + bv;
    }
  }
}

// ---------------- flash attention v3: swapped-QK in-register softmax --------------
// Block = (b,h) x 64 Q rows, 4 waves x 16 rows. K/V LDS double-buffered (as before).
// QK^T computed SWAPPED: sacc[n] = mfma(K-frag, Q-frag) -> D[kv][q]: each lane owns
// 16 P values (kv = s0+16n+g*4+r) of ONE q-row (q0+lr). Row-max = 15 local fmax +
// 2 shfl; P->bf16 via v_cvt_pk_bf16_f32; P^T repacked to PV B-operand fragments
// in-register via 16 shfl + 8 selects (no Ps LDS). PV swapped: mfma(V^T, P^T) ->
// D[d][q]. m_r/l_r are per-lane scalars. Epilogue transposes on store.
__global__ __launch_bounds__(256) void attn_kernel(
    const u16* __restrict__ Qb, const u16* __restrict__ Kb, const u16* __restrict__ VTb,
    const float* __restrict__ mask, u16* __restrict__ AO) {
  __shared__ __attribute__((aligned(16))) u16 Ks[2][64 * 128];
  __shared__ __attribute__((aligned(16))) u16 Vs[2][128 * 64];
  __shared__ float bias_lds[S_];

  int t = threadIdx.x, w = t >> 6, lane = t & 63;
  int g = lane >> 4, lr = lane & 15;
  int sw = swz_id();                 // group same-(b,h) blocks per XCD
  int qt = sw & 31, bh = sw >> 5;
  int b = bh >> 4;
  const u16* Qh = Qb + (size_t)bh * S_ * DH_;
  const u16* Kh = Kb + (size_t)bh * S_ * DH_;
  const u16* Vh = VTb + (size_t)bh * DH_ * S_;
  int q0 = qt * 64 + w * 16;

  for (int i = t; i < S_; i += 256)
    bias_lds[i] = (1.0f - mask[b * S_ + i]) * BIASF;

  // Q fragments (used as the B-operand of swapped QK^T; same lane layout as A)
  bf16x8 bq[4];
#pragma unroll
  for (int kk = 0; kk < 4; ++kk)
    bq[kk] = *reinterpret_cast<const bf16x8*>(Qh + (size_t)(q0 + lr) * DH_ + kk * 32 + g * 8);

  f32x4 oacc[8] = {};
  float m_r = -1e30f, l_r = 0.f;

  __syncthreads();   // bias_lds visible

#define STAGE_KV(buf, s0base)                                                    \
  {                                                                              \
    _Pragma("unroll")                                                            \
    for (int i = 0; i < 4; ++i) {                                                \
      int idx = i * 256 + t;                                                     \
      int row = idx >> 4, slot = idx & 15;                                       \
      GL2LDS(Kh + (size_t)((s0base) + row) * DH_ + ((slot ^ (row & 7)) * 8),     \
             &Ks[buf][idx * 8]);                                                 \
    }                                                                            \
    _Pragma("unroll")                                                            \
    for (int i = 0; i < 4; ++i) {                                                \
      int idx = i * 256 + t;                                                     \
      int row = idx >> 3, slot = idx & 7;                                        \
      GL2LDS(Vh + (size_t)row * S_ + (s0base) + ((slot ^ (row & 7)) * 8),        \
             &Vs[buf][idx * 8]);                                                 \
    }                                                                            \
  }

  STAGE_KV(0, 0);
  const int NT = S_ / 64;
  for (int it = 0; it < NT; ++it) {
    int cur = it & 1;
    if (it + 1 < NT) {
      STAGE_KV(cur ^ 1, (it + 1) * 64);
      asm volatile("s_waitcnt vmcnt(8)" ::: "memory");
    } else {
      asm volatile("s_waitcnt vmcnt(0)" ::: "memory");
    }
    __builtin_amdgcn_s_barrier();
    __builtin_amdgcn_sched_barrier(0);

    // QK^T swapped: sacc[n] = K-frag(n) x Q -> D[kv 16n..][q]; lane: q=lr fixed
    f32x4 sacc[4] = {};
    __builtin_amdgcn_s_setprio(1);
#pragma unroll
    for (int kk = 0; kk < 4; ++kk) {
#pragma unroll
      for (int n = 0; n < 4; ++n) {
        int row = lr + 16 * n;
        bf16x8 ak = *reinterpret_cast<const bf16x8*>(
            &Ks[cur][row * 128 + ((((kk << 2) | g) ^ (row & 7)) * 8)]);
        sacc[n] = __builtin_amdgcn_mfma_f32_16x16x32_bf16(ak, bq[kk], sacc[n], 0, 0, 0);
      }
    }
    __builtin_amdgcn_s_setprio(0);

    int s0 = it * 64;
    float sv[4][4];
    float mloc = -3e38f;
#pragma unroll
    for (int n = 0; n < 4; ++n) {
      float4 bb = *reinterpret_cast<const float4*>(&bias_lds[s0 + 16 * n + g * 4]);
      sv[n][0] = sacc[n][0] + bb.x; sv[n][1] = sacc[n][1] + bb.y;
      sv[n][2] = sacc[n][2] + bb.z; sv[n][3] = sacc[n][3] + bb.w;
      mloc = fmaxf(mloc, fmaxf(fmaxf(sv[n][0], sv[n][1]), fmaxf(sv[n][2], sv[n][3])));
    }
    float mx = fmaxf(mloc, __shfl_xor(mloc, 16));
    mx = fmaxf(mx, __shfl_xor(mx, 32));

    // defer-max: rescale only if this lane's row grew by >8 (log2 units)
    if (__any(mx - m_r > 8.f)) {
      float mnew = fmaxf(m_r, mx);
      float f = fast_exp2(m_r - mnew);
      m_r = mnew;
      l_r *= f;
#pragma unroll
      for (int no = 0; no < 8; ++no) oacc[no] *= f;
    }

    unsigned pku[4][2];
#pragma unroll
    for (int n = 0; n < 4; ++n) {
      float p0 = fast_exp2(sv[n][0] - m_r), p1 = fast_exp2(sv[n][1] - m_r);
      float p2 = fast_exp2(sv[n][2] - m_r), p3 = fast_exp2(sv[n][3] - m_r);
      l_r += (p0 + p1) + (p2 + p3);
      pku[n][0] = cvtpk(p0, p1);
      pku[n][1] = cvtpk(p2, p3);
    }

    // PV swapped: oacc[no] += V^T-frag(no) x P^T. Repack P^T into B-operand:
    // dest lane (g,lr) kk2 needs kv'=kk2*32+g*8+j from src lanes (2(g&1)(+1), lr),
    // register n' = 2*kk2 + (g>>1).
    int srcA = ((g & 1) << 5) + lr;
    int srcB = srcA + 16;
    bool hi = (g >> 1) != 0;
#pragma unroll
    for (int kk2 = 0; kk2 < 2; ++kk2) {
      unsigned a0 = __shfl(pku[2 * kk2][0], srcA), a1 = __shfl(pku[2 * kk2 + 1][0], srcA);
      unsigned b0 = __shfl(pku[2 * kk2][1], srcA), b1 = __shfl(pku[2 * kk2 + 1][1], srcA);
      unsigned c0 = __shfl(pku[2 * kk2][0], srcB), c1 = __shfl(pku[2 * kk2 + 1][0], srcB);
      unsigned d0 = __shfl(pku[2 * kk2][1], srcB), d1 = __shfl(pku[2 * kk2 + 1][1], srcB);
      union { uint4 u; bf16x8 v; } pa;
      pa.u.x = hi ? a1 : a0; pa.u.y = hi ? b1 : b0;
      pa.u.z = hi ? c1 : c0; pa.u.w = hi ? d1 : d0;
      __builtin_amdgcn_s_setprio(1);
#pragma unroll
      for (int no = 0; no < 8; ++no) {
        int d = lr + 16 * no;
        bf16x8 av = *reinterpret_cast<const bf16x8*>(
            &Vs[cur][d * 64 + ((((kk2 << 2) | g) ^ (d & 7)) * 8)]);
        oacc[no] = __builtin_amdgcn_mfma_f32_16x16x32_bf16(av, pa.v, oacc[no], 0, 0, 0);
      }
      __builtin_amdgcn_s_setprio(0);
    }
    __builtin_amdgcn_sched_barrier(0);
    __builtin_amdgcn_s_barrier();
  }
#undef STAGE_KV

  // epilogue: lane holds out[d = 16no+g*4+r][q = q0+lr]; l_r partial over its kv set
  float s = l_r;
  s += __shfl_xor(s, 16);
  s += __shfl_xor(s, 32);
  float inv = 1.0f / s;
  int h = bh & 15;
  int q = q0 + lr;
  u16* dst = AO + ((size_t)(b * S_ + q)) * D_ + h * DH_ + g * 4;
#pragma unroll
  for (int no = 0; no < 8; ++no) {
    ushort4 pk4;
    pk4.x = f2bf(oacc[no][0] * inv); pk4.y = f2bf(oacc[no][1] * inv);
    pk4.z = f2bf(oacc[no][2] * inv); pk4.w = f2bf(oacc[no][3] * inv);
    *reinterpret_cast<ushort4*>(dst + 16 * no) = pk4;
  }
}

extern "C" void kernel_launch(void* const* d_in, const int* in_sizes, int n_in,
                              void* d_out, int out_size, void* d_ws, size_t ws_size,
                              hipStream_t stream) {
  const float* h_in   = (const float*)d_in[0];
  const float* mask   = (const float*)d_in[1];
  const float* w_attn = (const float*)d_in[2];
  const float* b_attn = (const float*)d_in[3];
  const float* w_proj = (const float*)d_in[4];
  const float* b_proj = (const float*)d_in[5];
  float* out = (float*)d_out;

  char* ws = (char*)d_ws;
  u16* Hb  = (u16*)(ws);                       // 16 MiB: H bf16 [4096][2048]
  u16* W1T = (u16*)(ws + 16777216);            // 24 MiB: Wattn^T bf16 [6144][2048]
  u16* W2T = (u16*)(ws + 41943040);            //  8 MiB: Wproj^T bf16 [2048][2048]
  u16* Qb  = (u16*)(ws + 50331648);            // 16 MiB: Q (prescaled) [B][H][S][128]
  u16* Kb  = (u16*)(ws + 67108864);            // 16 MiB: K  [B][H][S][128]
  u16* VTb = (u16*)(ws + 83886080);            // 16 MiB: V^T [B][H][128][S]
  u16* AO  = Hb;  // reuse H region for attention output (H dead after gemm_qkv)

  cvt_kernel<<<2048, 256, 0, stream>>>(h_in, Hb, (B_ * S_ * D_) / 4);
  dim3 tb(32, 8);
  transpose_kernel<<<dim3(N3_ / 32, D_ / 32), tb, 0, stream>>>(w_attn, W1T, D_, N3_);
  transpose_kernel<<<dim3(D_ / 32, D_ / 32), tb, 0, stream>>>(w_proj, W2T, D_, D_);
  gemm_qkv_kernel<<<dim3(N3_ / 128, (B_ * S_) / 256), 512, 0, stream>>>(
      Hb, W1T, b_attn, Qb, Kb, VTb);
  attn_kernel<<<dim3(S_ / 64, B_ * NH_), 256, 0, stream>>>(Qb, Kb, VTb, mask, AO);
  gemm_proj_kernel<<<dim3(D_ / 128, (B_ * S_) / 256), 512, 0, stream>>>(AO, W2T, b_proj, out);
}

// Round 10
// 424.946 us; speedup vs baseline: 1.1500x; 1.0230x over previous
//
#include <hip/hip_runtime.h>
#include <stdint.h>

// Problem constants
#define B_   2
#define S_   2048
#define D_   2048
#define NH_  16
#define DH_  128
#define N3_  6144

typedef unsigned short u16;
typedef __bf16 bf16x8 __attribute__((ext_vector_type(8)));
typedef float  f32x4  __attribute__((ext_vector_type(4)));

#define QSCALE   (0.08838834764831845f * 1.4426950408889634f)  // 1/sqrt(128) * log2(e)
#define BIASF    (-10000.0f * 1.4426950408889634f)

__device__ __forceinline__ u16 f2bf(float f) {
  union { float f; unsigned u; } v; v.f = f;
  unsigned u = v.u;
  return (u16)((u + 0x7FFFu + ((u >> 16) & 1u)) >> 16);
}

__device__ __forceinline__ float fast_exp2(float x) {
  float r;
  asm("v_exp_f32 %0, %1" : "=v"(r) : "v"(x));
  return r;
}

__device__ __forceinline__ unsigned cvtpk(float lo, float hi) {
  unsigned r;
  asm("v_cvt_pk_bf16_f32 %0, %1, %2" : "=v"(r) : "v"(lo), "v"(hi));
  return r;
}

// async global->LDS, 16B per lane; LDS dest must be wave-uniform-base + lane*16
#define GL2LDS(gsrc, ldst)                                                              \
  __builtin_amdgcn_global_load_lds((const __attribute__((address_space(1))) void*)(gsrc), \
      (__attribute__((address_space(3))) void*)(ldst), 16, 0, 0)

// XCD-aware block swizzle: contiguous logical chunk per XCD. Requires total%8==0.
__device__ __forceinline__ int swz_id() {
  int id = blockIdx.y * gridDim.x + blockIdx.x;
  int cpx = (gridDim.x * gridDim.y) >> 3;
  return (id & 7) * cpx + (id >> 3);
}

// ---------------- fp32 -> bf16 convert (vectorized) ----------------
__global__ void cvt_kernel(const float* __restrict__ in, u16* __restrict__ out, int n4) {
  int i = blockIdx.x * blockDim.x + threadIdx.x;
  int stride = gridDim.x * blockDim.x;
  for (; i < n4; i += stride) {
    float4 v = ((const float4*)in)[i];
    ushort4 o;
    o.x = f2bf(v.x); o.y = f2bf(v.y); o.z = f2bf(v.z); o.w = f2bf(v.w);
    ((ushort4*)out)[i] = o;
  }
}

// ---------------- fp32 [K][N] -> bf16 [N][K] transpose ----------------
__global__ void transpose_kernel(const float* __restrict__ in, u16* __restrict__ out,
                                 int K, int N) {
  __shared__ float tile[32][33];
  int tx = threadIdx.x, ty = threadIdx.y;
  int nx = blockIdx.x * 32, ky = blockIdx.y * 32;
#pragma unroll
  for (int j = 0; j < 32; j += 8)
    tile[ty + j][tx] = in[(size_t)(ky + ty + j) * N + nx + tx];
  __syncthreads();
#pragma unroll
  for (int j = 0; j < 32; j += 8)
    out[(size_t)(nx + ty + j) * K + ky + tx] = f2bf(tile[tx][ty + j]);
}

// ========== 8-phase deep-pipelined GEMM: BM=256 x BN=128, BK=64 ==================
// 512 thr = 8 waves (4M x 2N), wave tile 64x64, acc[4][4]. LDS 96 KiB: per buf c
// (c = tile&1): A-quadhalf qm = rows {r: (r>>5)&1==qm} packed [128][64] (16KiB),
// B = [128 n][64] (16KiB). XOR swizzle slot = L ^ (row&7) (pre-swizzled global src,
// linear LDS dest; reads apply same XOR).
// Cycle j computes tiles 2j (buf0: ph1=Q0, ph2=Q1) and 2j+1 (buf1: ph3, ph4).
// Per phase: [ds-reads][1 half-tile stage (2 gloads)][VMCNT(6)][BAR][LGKM0]
//            [16 MFMA setprio][BAR]  -- loads stay in flight ~4 phases (T3+T4).
// Stage slots: ph1: A-Q1(2j+1)  ph2: A-Q0(2j+2)+B(2j+2)  ph3: A-Q1(2j+2)
//              ph4: A-Q0(2j+3)+B(2j+3)   (each exactly 1 barrier after the
// overwritten half's last reader drained -- verified). FIFO drain table: VMCNT(6)
// at each phase end drains exactly the half needed one phase later (outstanding
// 8/10 -> 6). Tail: peeled epilogue for tiles NT-2, NT-1 (stage A-Q1(NT-1),
// vmcnt(0), bar, pure reads+MFMA, no barriers needed).
// ==================================================================================

#define G8_AB(c, qm) (lds + (c) * 24576 + (qm) * 8192)
#define G8_BB(c)     (lds + (c) * 24576 + 16384)
#define VMCNT(n) asm volatile("s_waitcnt vmcnt(" #n ")" ::: "memory")
#define LGKM0                                            \
  do {                                                   \
    asm volatile("s_waitcnt lgkmcnt(0)" ::: "memory");   \
    __builtin_amdgcn_sched_barrier(0);                   \
  } while (0)
#define BAR __builtin_amdgcn_s_barrier()

template <int KD>
__device__ __forceinline__ void stage_ah(const u16* __restrict__ A, u16* lds,
                                         int k, int qm, int m0, int t) {
  int c = k & 1;
#pragma unroll
  for (int inst = 0; inst < 2; ++inst) {
    int idx = inst * 512 + t;
    int hr = idx >> 3, p = idx & 7, L = p ^ (hr & 7);
    int r = ((hr >> 5) << 6) + qm * 32 + (hr & 31);
    GL2LDS(A + (size_t)(m0 + r) * KD + k * 64 + L * 8,
           G8_AB(c, qm) + idx * 8);
  }
}

template <int KD>
__device__ __forceinline__ void stage_bh(const u16* __restrict__ BT, u16* lds,
                                         int k, int n0, int t) {
  int c = k & 1;
#pragma unroll
  for (int inst = 0; inst < 2; ++inst) {
    int idx = inst * 512 + t;
    int hn = idx >> 3, p = idx & 7, L = p ^ (hn & 7);
    GL2LDS(BT + (size_t)(n0 + hn) * KD + k * 64 + L * 8,
           G8_BB(c) + idx * 8);
  }
}

__device__ __forceinline__ void read_aq(const u16* lds, int c, int qm, int wr, int g,
                                        int lr, bf16x8 (&af)[2][2]) {
  const u16* base = G8_AB(c, qm);
#pragma unroll
  for (int i = 0; i < 2; ++i) {
    int hr = wr * 32 + i * 16 + lr;
#pragma unroll
    for (int kk = 0; kk < 2; ++kk) {
      int slot = ((kk << 2) | g) ^ (hr & 7);
      af[i][kk] = *reinterpret_cast<const bf16x8*>(base + hr * 64 + slot * 8);
    }
  }
}

__device__ __forceinline__ void read_b(const u16* lds, int c, int wc, int g, int lr,
                                       bf16x8 (&bf)[4][2]) {
  const u16* base = G8_BB(c);
#pragma unroll
  for (int nj = 0; nj < 4; ++nj) {
    int hn = wc * 64 + nj * 16 + lr;
#pragma unroll
    for (int kk = 0; kk < 2; ++kk) {
      int slot = ((kk << 2) | g) ^ (hn & 7);
      bf[nj][kk] = *reinterpret_cast<const bf16x8*>(base + hn * 64 + slot * 8);
    }
  }
}

template <int QM>
__device__ __forceinline__ void mfma_q(const bf16x8 (&af)[2][2], const bf16x8 (&bf)[4][2],
                                       f32x4 (&acc)[4][4]) {
  __builtin_amdgcn_s_setprio(1);
#pragma unroll
  for (int i = 0; i < 2; ++i)
#pragma unroll
    for (int nj = 0; nj < 4; ++nj)
#pragma unroll
      for (int kk = 0; kk < 2; ++kk)
        acc[QM * 2 + i][nj] = __builtin_amdgcn_mfma_f32_16x16x32_bf16(
            af[i][kk], bf[nj][kk], acc[QM * 2 + i][nj], 0, 0, 0);
  __builtin_amdgcn_s_setprio(0);
}

template <int KD>
__device__ __forceinline__ void gemm8_core(const u16* __restrict__ A,
                                           const u16* __restrict__ BT,
                                           int m0, int n0, u16* lds, f32x4 (&acc)[4][4]) {
  const int NT = KD / 64;   // 32
  const int NC = NT / 2;    // 16
  int t = threadIdx.x, wv = t >> 6, lane = t & 63;
  int g = lane >> 4, lr = lane & 15;
  int wr = wv >> 1, wc = wv & 1;
  bf16x8 af[2][2], bf[4][2];

  // prologue: tiles 0 (buf0), 1 (buf1) fully staged; drain; barrier
  stage_ah<KD>(A, lds, 0, 0, m0, t);
  stage_ah<KD>(A, lds, 0, 1, m0, t);
  stage_bh<KD>(BT, lds, 0, n0, t);
  stage_ah<KD>(A, lds, 1, 0, m0, t);
  stage_ah<KD>(A, lds, 1, 1, m0, t);
  stage_bh<KD>(BT, lds, 1, n0, t);
  VMCNT(0);
  BAR;

  for (int j = 0; j + 1 < NC; ++j) {
    // ph1: tile 2j quadrant 0
    read_aq(lds, 0, 0, wr, g, lr, af);
    read_b(lds, 0, wc, g, lr, bf);
    if (j >= 1) stage_ah<KD>(A, lds, 2 * j + 1, 1, m0, t);
    VMCNT(6); BAR; LGKM0;
    mfma_q<0>(af, bf, acc);
    BAR;
    // ph2: tile 2j quadrant 1 (B kept in regs)
    read_aq(lds, 0, 1, wr, g, lr, af);
    stage_ah<KD>(A, lds, 2 * j + 2, 0, m0, t);
    stage_bh<KD>(BT, lds, 2 * j + 2, n0, t);
    VMCNT(6); BAR; LGKM0;
    mfma_q<1>(af, bf, acc);
    BAR;
    // ph3: tile 2j+1 quadrant 0
    read_aq(lds, 1, 0, wr, g, lr, af);
    read_b(lds, 1, wc, g, lr, bf);
    stage_ah<KD>(A, lds, 2 * j + 2, 1, m0, t);
    VMCNT(6); BAR; LGKM0;
    mfma_q<0>(af, bf, acc);
    BAR;
    // ph4: tile 2j+1 quadrant 1
    read_aq(lds, 1, 1, wr, g, lr, af);
    if (2 * j + 3 < NT) {
      stage_ah<KD>(A, lds, 2 * j + 3, 0, m0, t);
      stage_bh<KD>(BT, lds, 2 * j + 3, n0, t);
    }
    VMCNT(6); BAR; LGKM0;
    mfma_q<1>(af, bf, acc);
    BAR;
  }

  // epilogue: tiles NT-2 (buf0), NT-1 (buf1); A-Q1(NT-1) still unstaged
  stage_ah<KD>(A, lds, NT - 1, 1, m0, t);
  VMCNT(0);
  BAR;
  read_aq(lds, 0, 0, wr, g, lr, af);
  read_b(lds, 0, wc, g, lr, bf);
  mfma_q<0>(af, bf, acc);
  read_aq(lds, 0, 1, wr, g, lr, af);
  mfma_q<1>(af, bf, acc);
  read_aq(lds, 1, 0, wr, g, lr, af);
  read_b(lds, 1, wc, g, lr, bf);
  mfma_q<0>(af, bf, acc);
  read_aq(lds, 1, 1, wr, g, lr, af);
  mfma_q<1>(af, bf, acc);
}

// ---------------- GEMM1: H @ Wattn + b -> scatter Q (prescaled), K, V^T ----------------
__global__ __launch_bounds__(512, 1) void gemm_qkv_kernel(
    const u16* __restrict__ A, const u16* __restrict__ BT, const float* __restrict__ bias,
    u16* __restrict__ Qb, u16* __restrict__ Kb, u16* __restrict__ VTb) {
  __shared__ __attribute__((aligned(16))) u16 lds[49152];
  f32x4 acc[4][4] = {};
  int sw = swz_id();
  int n0 = (sw % gridDim.x) * 128, m0 = (sw / gridDim.x) * 256;
  gemm8_core<2048>(A, BT, m0, n0, lds, acc);
  int t = threadIdx.x, lane = t & 63, wv = t >> 6;
  int g = lane >> 4, lr = lane & 15;
  int wrB = (wv >> 1) * 64, wcB = (wv & 1) * 64;
#pragma unroll
  for (int mi = 0; mi < 4; ++mi) {
    int rowbase = m0 + wrB + mi * 16 + g * 4;
    int b = rowbase >> 11, s = rowbase & 2047;
#pragma unroll
    for (int nj = 0; nj < 4; ++nj) {
      int col = n0 + wcB + nj * 16 + lr;
      float bv = bias[col];
      int sec = col >> 11;            // 0=Q 1=K 2=V
      int within = col & 2047;
      int h = within >> 7, d = within & 127;
      if (sec < 2) {
        float mult = (sec == 0) ? QSCALE : 1.0f;   // fold 1/sqrt(dh)*log2e into Q
        u16* dst = (sec == 0 ? Qb : Kb) + ((size_t)(b * NH_ + h) * S_ + s) * DH_ + d;
#pragma unroll
        for (int r = 0; r < 4; ++r) dst[(size_t)r * DH_] = f2bf((acc[mi][nj][r] + bv) * mult);
      } else {
        u16* dst = VTb + ((size_t)(b * NH_ + h) * DH_ + d) * S_ + s;  // V transposed
        ushort4 pk;
        pk.x = f2bf(acc[mi][nj][0] + bv); pk.y = f2bf(acc[mi][nj][1] + bv);
        pk.z = f2bf(acc[mi][nj][2] + bv); pk.w = f2bf(acc[mi][nj][3] + bv);
        *reinterpret_cast<ushort4*>(dst) = pk;
      }
    }
  }
}

// ---------------- GEMM2: AO @ Wproj + b -> fp32 out ----------------
__global__ __launch_bounds__(512, 1) void gemm_proj_kernel(
    const u16* __restrict__ A, const u16* __restrict__ BT, const float* __restrict__ bias,
    float* __restrict__ out) {
  __shared__ __attribute__((aligned(16))) u16 lds[49152];
  f32x4 acc[4][4] = {};
  int sw = swz_id();
  int n0 = (sw % gridDim.x) * 128, m0 = (sw / gridDim.x) * 256;
  gemm8_core<2048>(A, BT, m0, n0, lds, acc);
  int t = threadIdx.x, lane = t & 63, wv = t >> 6;
  int g = lane >> 4, lr = lane & 15;
  int wrB = (wv >> 1) * 64, wcB = (wv & 1) * 64;
#pragma unroll
  for (int mi = 0; mi < 4; ++mi) {
    int rowbase = m0 + wrB + mi * 16 + g * 4;
#pragma unroll
    for (int nj = 0; nj < 4; ++nj) {
      int col = n0 + wcB + nj * 16 + lr;
      float bv = bias[col];
      float* dst = out + (size_t)rowbase * D_ + col;
#pragma unroll
      for (int r = 0; r < 4; ++r) dst[(size_t)r * D_] = acc[mi][nj][r] + bv;
    }
  }
}

// ---------------- flash attention v3: swapped-QK in-register softmax (unchanged) --
__global__ __launch_bounds__(256) void attn_kernel(
    const u16* __restrict__ Qb, const u16* __restrict__ Kb, const u16* __restrict__ VTb,
    const float* __restrict__ mask, u16* __restrict__ AO) {
  __shared__ __attribute__((aligned(16))) u16 Ks[2][64 * 128];
  __shared__ __attribute__((aligned(16))) u16 Vs[2][128 * 64];
  __shared__ float bias_lds[S_];

  int t = threadIdx.x, w = t >> 6, lane = t & 63;
  int g = lane >> 4, lr = lane & 15;
  int sw = swz_id();                 // group same-(b,h) blocks per XCD
  int qt = sw & 31, bh = sw >> 5;
  int b = bh >> 4;
  const u16* Qh = Qb + (size_t)bh * S_ * DH_;
  const u16* Kh = Kb + (size_t)bh * S_ * DH_;
  const u16* Vh = VTb + (size_t)bh * DH_ * S_;
  int q0 = qt * 64 + w * 16;

  for (int i = t; i < S_; i += 256)
    bias_lds[i] = (1.0f - mask[b * S_ + i]) * BIASF;

  bf16x8 bq[4];
#pragma unroll
  for (int kk = 0; kk < 4; ++kk)
    bq[kk] = *reinterpret_cast<const bf16x8*>(Qh + (size_t)(q0 + lr) * DH_ + kk * 32 + g * 8);

  f32x4 oacc[8] = {};
  float m_r = -1e30f, l_r = 0.f;

  __syncthreads();   // bias_lds visible

#define STAGE_KV(buf, s0base)                                                    \
  {                                                                              \
    _Pragma("unroll")                                                            \
    for (int i = 0; i < 4; ++i) {                                                \
      int idx = i * 256 + t;                                                     \
      int row = idx >> 4, slot = idx & 15;                                       \
      GL2LDS(Kh + (size_t)((s0base) + row) * DH_ + ((slot ^ (row & 7)) * 8),     \
             &Ks[buf][idx * 8]);                                                 \
    }                                                                            \
    _Pragma("unroll")                                                            \
    for (int i = 0; i < 4; ++i) {                                                \
      int idx = i * 256 + t;                                                     \
      int row = idx >> 3, slot = idx & 7;                                        \
      GL2LDS(Vh + (size_t)row * S_ + (s0base) + ((slot ^ (row & 7)) * 8),        \
             &Vs[buf][idx * 8]);                                                 \
    }                                                                            \
  }

  STAGE_KV(0, 0);
  const int NT = S_ / 64;
  for (int it = 0; it < NT; ++it) {
    int cur = it & 1;
    if (it + 1 < NT) {
      STAGE_KV(cur ^ 1, (it + 1) * 64);
      asm volatile("s_waitcnt vmcnt(8)" ::: "memory");
    } else {
      asm volatile("s_waitcnt vmcnt(0)" ::: "memory");
    }
    __builtin_amdgcn_s_barrier();
    __builtin_amdgcn_sched_barrier(0);

    f32x4 sacc[4] = {};
    __builtin_amdgcn_s_setprio(1);
#pragma unroll
    for (int kk = 0; kk < 4; ++kk) {
#pragma unroll
      for (int n = 0; n < 4; ++n) {
        int row = lr + 16 * n;
        bf16x8 ak = *reinterpret_cast<const bf16x8*>(
            &Ks[cur][row * 128 + ((((kk << 2) | g) ^ (row & 7)) * 8)]);
        sacc[n] = __builtin_amdgcn_mfma_f32_16x16x32_bf16(ak, bq[kk], sacc[n], 0, 0, 0);
      }
    }
    __builtin_amdgcn_s_setprio(0);

    int s0 = it * 64;
    float sv[4][4];
    float mloc = -3e38f;
#pragma unroll
    for (int n = 0; n < 4; ++n) {
      float4 bb = *reinterpret_cast<const float4*>(&bias_lds[s0 + 16 * n + g * 4]);
      sv[n][0] = sacc[n][0] + bb.x; sv[n][1] = sacc[n][1] + bb.y;
      sv[n][2] = sacc[n][2] + bb.z; sv[n][3] = sacc[n][3] + bb.w;
      mloc = fmaxf(mloc, fmaxf(fmaxf(sv[n][0], sv[n][1]), fmaxf(sv[n][2], sv[n][3])));
    }
    float mx = fmaxf(mloc, __shfl_xor(mloc, 16));
    mx = fmaxf(mx, __shfl_xor(mx, 32));

    if (__any(mx - m_r > 8.f)) {
      float mnew = fmaxf(m_r, mx);
      float f = fast_exp2(m_r - mnew);
      m_r = mnew;
      l_r *= f;
#pragma unroll
      for (int no = 0; no < 8; ++no) oacc[no] *= f;
    }

    unsigned pku[4][2];
#pragma unroll
    for (int n = 0; n < 4; ++n) {
      float p0 = fast_exp2(sv[n][0] - m_r), p1 = fast_exp2(sv[n][1] - m_r);
      float p2 = fast_exp2(sv[n][2] - m_r), p3 = fast_exp2(sv[n][3] - m_r);
      l_r += (p0 + p1) + (p2 + p3);
      pku[n][0] = cvtpk(p0, p1);
      pku[n][1] = cvtpk(p2, p3);
    }

    int srcA = ((g & 1) << 5) + lr;
    int srcB = srcA + 16;
    bool hi = (g >> 1) != 0;
#pragma unroll
    for (int kk2 = 0; kk2 < 2; ++kk2) {
      unsigned a0 = __shfl(pku[2 * kk2][0], srcA), a1 = __shfl(pku[2 * kk2 + 1][0], srcA);
      unsigned b0 = __shfl(pku[2 * kk2][1], srcA), b1 = __shfl(pku[2 * kk2 + 1][1], srcA);
      unsigned c0 = __shfl(pku[2 * kk2][0], srcB), c1 = __shfl(pku[2 * kk2 + 1][0], srcB);
      unsigned d0 = __shfl(pku[2 * kk2][1], srcB), d1 = __shfl(pku[2 * kk2 + 1][1], srcB);
      union { uint4 u; bf16x8 v; } pa;
      pa.u.x = hi ? a1 : a0; pa.u.y = hi ? b1 : b0;
      pa.u.z = hi ? c1 : c0; pa.u.w = hi ? d1 : d0;
      __builtin_amdgcn_s_setprio(1);
#pragma unroll
      for (int no = 0; no < 8; ++no) {
        int d = lr + 16 * no;
        bf16x8 av = *reinterpret_cast<const bf16x8*>(
            &Vs[cur][d * 64 + ((((kk2 << 2) | g) ^ (d & 7)) * 8)]);
        oacc[no] = __builtin_amdgcn_mfma_f32_16x16x32_bf16(av, pa.v, oacc[no], 0, 0, 0);
      }
      __builtin_amdgcn_s_setprio(0);
    }
    __builtin_amdgcn_sched_barrier(0);
    __builtin_amdgcn_s_barrier();
  }
#undef STAGE_KV

  float s = l_r;
  s += __shfl_xor(s, 16);
  s += __shfl_xor(s, 32);
  float inv = 1.0f / s;
  int h = bh & 15;
  int q = q0 + lr;
  u16* dst = AO + ((size_t)(b * S_ + q)) * D_ + h * DH_ + g * 4;
#pragma unroll
  for (int no = 0; no < 8; ++no) {
    ushort4 pk4;
    pk4.x = f2bf(oacc[no][0] * inv); pk4.y = f2bf(oacc[no][1] * inv);
    pk4.z = f2bf(oacc[no][2] * inv); pk4.w = f2bf(oacc[no][3] * inv);
    *reinterpret_cast<ushort4*>(dst + 16 * no) = pk4;
  }
}

extern "C" void kernel_launch(void* const* d_in, const int* in_sizes, int n_in,
                              void* d_out, int out_size, void* d_ws, size_t ws_size,
                              hipStream_t stream) {
  const float* h_in   = (const float*)d_in[0];
  const float* mask   = (const float*)d_in[1];
  const float* w_attn = (const float*)d_in[2];
  const float* b_attn = (const float*)d_in[3];
  const float* w_proj = (const float*)d_in[4];
  const float* b_proj = (const float*)d_in[5];
  float* out = (float*)d_out;

  char* ws = (char*)d_ws;
  u16* Hb  = (u16*)(ws);                       // 16 MiB: H bf16 [4096][2048]
  u16* W1T = (u16*)(ws + 16777216);            // 24 MiB: Wattn^T bf16 [6144][2048]
  u16* W2T = (u16*)(ws + 41943040);            //  8 MiB: Wproj^T bf16 [2048][2048]
  u16* Qb  = (u16*)(ws + 50331648);            // 16 MiB: Q (prescaled) [B][H][S][128]
  u16* Kb  = (u16*)(ws + 67108864);            // 16 MiB: K  [B][H][S][128]
  u16* VTb = (u16*)(ws + 83886080);            // 16 MiB: V^T [B][H][128][S]
  u16* AO  = Hb;  // reuse H region for attention output (H dead after gemm_qkv)

  cvt_kernel<<<2048, 256, 0, stream>>>(h_in, Hb, (B_ * S_ * D_) / 4);
  dim3 tb(32, 8);
  transpose_kernel<<<dim3(N3_ / 32, D_ / 32), tb, 0, stream>>>(w_attn, W1T, D_, N3_);
  transpose_kernel<<<dim3(D_ / 32, D_ / 32), tb, 0, stream>>>(w_proj, W2T, D_, D_);
  gemm_qkv_kernel<<<dim3(N3_ / 128, (B_ * S_) / 256), 512, 0, stream>>>(
      Hb, W1T, b_attn, Qb, Kb, VTb);
  attn_kernel<<<dim3(S_ / 64, B_ * NH_), 256, 0, stream>>>(Qb, Kb, VTb, mask, AO);
  gemm_proj_kernel<<<dim3(D_ / 128, (B_ * S_) / 256), 512, 0, stream>>>(AO, W2T, b_proj, out);
}

// Round 11
// 400.457 us; speedup vs baseline: 1.2203x; 1.0612x over previous
//
#include <hip/hip_runtime.h>
#include <stdint.h>

// Problem constants
#define B_   2
#define S_   2048
#define D_   2048
#define NH_  16
#define DH_  128
#define N3_  6144

typedef unsigned short u16;
typedef __bf16 bf16x8 __attribute__((ext_vector_type(8)));
typedef float  f32x4  __attribute__((ext_vector_type(4)));

#define QSCALE   (0.08838834764831845f * 1.4426950408889634f)  // 1/sqrt(128) * log2(e)
#define BIASF    (-10000.0f * 1.4426950408889634f)

__device__ __forceinline__ u16 f2bf(float f) {
  union { float f; unsigned u; } v; v.f = f;
  unsigned u = v.u;
  return (u16)((u + 0x7FFFu + ((u >> 16) & 1u)) >> 16);
}

__device__ __forceinline__ float fast_exp2(float x) {
  float r;
  asm("v_exp_f32 %0, %1" : "=v"(r) : "v"(x));
  return r;
}

__device__ __forceinline__ unsigned cvtpk(float lo, float hi) {
  unsigned r;
  asm("v_cvt_pk_bf16_f32 %0, %1, %2" : "=v"(r) : "v"(lo), "v"(hi));
  return r;
}

// async global->LDS, 16B per lane; LDS dest must be wave-uniform-base + lane*16
#define GL2LDS(gsrc, ldst)                                                              \
  __builtin_amdgcn_global_load_lds((const __attribute__((address_space(1))) void*)(gsrc), \
      (__attribute__((address_space(3))) void*)(ldst), 16, 0, 0)

// XCD-aware block swizzle: contiguous logical chunk per XCD. Requires total%8==0.
__device__ __forceinline__ int swz_id() {
  int id = blockIdx.y * gridDim.x + blockIdx.x;
  int cpx = (gridDim.x * gridDim.y) >> 3;
  return (id & 7) * cpx + (id >> 3);
}

// ---------------- fp32 -> bf16 convert (vectorized) ----------------
__global__ void cvt_kernel(const float* __restrict__ in, u16* __restrict__ out, int n4) {
  int i = blockIdx.x * blockDim.x + threadIdx.x;
  int stride = gridDim.x * blockDim.x;
  for (; i < n4; i += stride) {
    float4 v = ((const float4*)in)[i];
    ushort4 o;
    o.x = f2bf(v.x); o.y = f2bf(v.y); o.z = f2bf(v.z); o.w = f2bf(v.w);
    ((ushort4*)out)[i] = o;
  }
}

// ---------------- fp32 [K][N] -> bf16 [N][K] transpose ----------------
__global__ void transpose_kernel(const float* __restrict__ in, u16* __restrict__ out,
                                 int K, int N) {
  __shared__ float tile[32][33];
  int tx = threadIdx.x, ty = threadIdx.y;
  int nx = blockIdx.x * 32, ky = blockIdx.y * 32;
#pragma unroll
  for (int j = 0; j < 32; j += 8)
    tile[ty + j][tx] = in[(size_t)(ky + ty + j) * N + nx + tx];
  __syncthreads();
#pragma unroll
  for (int j = 0; j < 32; j += 8)
    out[(size_t)(nx + ty + j) * K + ky + tx] = f2bf(tile[tx][ty + j]);
}

// ========== 8-phase deep-pipelined GEMM: BM=256 x BN=128, BK=64 (unchanged R10) ===
#define G8_AB(c, qm) (lds + (c) * 24576 + (qm) * 8192)
#define G8_BB(c)     (lds + (c) * 24576 + 16384)
#define VMCNT(n) asm volatile("s_waitcnt vmcnt(" #n ")" ::: "memory")
#define LGKM0                                            \
  do {                                                   \
    asm volatile("s_waitcnt lgkmcnt(0)" ::: "memory");   \
    __builtin_amdgcn_sched_barrier(0);                   \
  } while (0)
#define BAR __builtin_amdgcn_s_barrier()

template <int KD>
__device__ __forceinline__ void stage_ah(const u16* __restrict__ A, u16* lds,
                                         int k, int qm, int m0, int t) {
  int c = k & 1;
#pragma unroll
  for (int inst = 0; inst < 2; ++inst) {
    int idx = inst * 512 + t;
    int hr = idx >> 3, p = idx & 7, L = p ^ (hr & 7);
    int r = ((hr >> 5) << 6) + qm * 32 + (hr & 31);
    GL2LDS(A + (size_t)(m0 + r) * KD + k * 64 + L * 8,
           G8_AB(c, qm) + idx * 8);
  }
}

template <int KD>
__device__ __forceinline__ void stage_bh(const u16* __restrict__ BT, u16* lds,
                                         int k, int n0, int t) {
  int c = k & 1;
#pragma unroll
  for (int inst = 0; inst < 2; ++inst) {
    int idx = inst * 512 + t;
    int hn = idx >> 3, p = idx & 7, L = p ^ (hn & 7);
    GL2LDS(BT + (size_t)(n0 + hn) * KD + k * 64 + L * 8,
           G8_BB(c) + idx * 8);
  }
}

__device__ __forceinline__ void read_aq(const u16* lds, int c, int qm, int wr, int g,
                                        int lr, bf16x8 (&af)[2][2]) {
  const u16* base = G8_AB(c, qm);
#pragma unroll
  for (int i = 0; i < 2; ++i) {
    int hr = wr * 32 + i * 16 + lr;
#pragma unroll
    for (int kk = 0; kk < 2; ++kk) {
      int slot = ((kk << 2) | g) ^ (hr & 7);
      af[i][kk] = *reinterpret_cast<const bf16x8*>(base + hr * 64 + slot * 8);
    }
  }
}

__device__ __forceinline__ void read_b(const u16* lds, int c, int wc, int g, int lr,
                                       bf16x8 (&bf)[4][2]) {
  const u16* base = G8_BB(c);
#pragma unroll
  for (int nj = 0; nj < 4; ++nj) {
    int hn = wc * 64 + nj * 16 + lr;
#pragma unroll
    for (int kk = 0; kk < 2; ++kk) {
      int slot = ((kk << 2) | g) ^ (hn & 7);
      bf[nj][kk] = *reinterpret_cast<const bf16x8*>(base + hn * 64 + slot * 8);
    }
  }
}

template <int QM>
__device__ __forceinline__ void mfma_q(const bf16x8 (&af)[2][2], const bf16x8 (&bf)[4][2],
                                       f32x4 (&acc)[4][4]) {
  __builtin_amdgcn_s_setprio(1);
#pragma unroll
  for (int i = 0; i < 2; ++i)
#pragma unroll
    for (int nj = 0; nj < 4; ++nj)
#pragma unroll
      for (int kk = 0; kk < 2; ++kk)
        acc[QM * 2 + i][nj] = __builtin_amdgcn_mfma_f32_16x16x32_bf16(
            af[i][kk], bf[nj][kk], acc[QM * 2 + i][nj], 0, 0, 0);
  __builtin_amdgcn_s_setprio(0);
}

template <int KD>
__device__ __forceinline__ void gemm8_core(const u16* __restrict__ A,
                                           const u16* __restrict__ BT,
                                           int m0, int n0, u16* lds, f32x4 (&acc)[4][4]) {
  const int NT = KD / 64;   // 32
  const int NC = NT / 2;    // 16
  int t = threadIdx.x, wv = t >> 6, lane = t & 63;
  int g = lane >> 4, lr = lane & 15;
  int wr = wv >> 1, wc = wv & 1;
  bf16x8 af[2][2], bf[4][2];

  stage_ah<KD>(A, lds, 0, 0, m0, t);
  stage_ah<KD>(A, lds, 0, 1, m0, t);
  stage_bh<KD>(BT, lds, 0, n0, t);
  stage_ah<KD>(A, lds, 1, 0, m0, t);
  stage_ah<KD>(A, lds, 1, 1, m0, t);
  stage_bh<KD>(BT, lds, 1, n0, t);
  VMCNT(0);
  BAR;

  for (int j = 0; j + 1 < NC; ++j) {
    read_aq(lds, 0, 0, wr, g, lr, af);
    read_b(lds, 0, wc, g, lr, bf);
    if (j >= 1) stage_ah<KD>(A, lds, 2 * j + 1, 1, m0, t);
    VMCNT(6); BAR; LGKM0;
    mfma_q<0>(af, bf, acc);
    BAR;
    read_aq(lds, 0, 1, wr, g, lr, af);
    stage_ah<KD>(A, lds, 2 * j + 2, 0, m0, t);
    stage_bh<KD>(BT, lds, 2 * j + 2, n0, t);
    VMCNT(6); BAR; LGKM0;
    mfma_q<1>(af, bf, acc);
    BAR;
    read_aq(lds, 1, 0, wr, g, lr, af);
    read_b(lds, 1, wc, g, lr, bf);
    stage_ah<KD>(A, lds, 2 * j + 2, 1, m0, t);
    VMCNT(6); BAR; LGKM0;
    mfma_q<0>(af, bf, acc);
    BAR;
    read_aq(lds, 1, 1, wr, g, lr, af);
    if (2 * j + 3 < NT) {
      stage_ah<KD>(A, lds, 2 * j + 3, 0, m0, t);
      stage_bh<KD>(BT, lds, 2 * j + 3, n0, t);
    }
    VMCNT(6); BAR; LGKM0;
    mfma_q<1>(af, bf, acc);
    BAR;
  }

  stage_ah<KD>(A, lds, NT - 1, 1, m0, t);
  VMCNT(0);
  BAR;
  read_aq(lds, 0, 0, wr, g, lr, af);
  read_b(lds, 0, wc, g, lr, bf);
  mfma_q<0>(af, bf, acc);
  read_aq(lds, 0, 1, wr, g, lr, af);
  mfma_q<1>(af, bf, acc);
  read_aq(lds, 1, 0, wr, g, lr, af);
  read_b(lds, 1, wc, g, lr, bf);
  mfma_q<0>(af, bf, acc);
  read_aq(lds, 1, 1, wr, g, lr, af);
  mfma_q<1>(af, bf, acc);
}

// ---------------- GEMM1: H @ Wattn + b -> scatter Q (prescaled), K, V^T ----------------
__global__ __launch_bounds__(512, 1) void gemm_qkv_kernel(
    const u16* __restrict__ A, const u16* __restrict__ BT, const float* __restrict__ bias,
    u16* __restrict__ Qb, u16* __restrict__ Kb, u16* __restrict__ VTb) {
  __shared__ __attribute__((aligned(16))) u16 lds[49152];
  f32x4 acc[4][4] = {};
  int sw = swz_id();
  int n0 = (sw % gridDim.x) * 128, m0 = (sw / gridDim.x) * 256;
  gemm8_core<2048>(A, BT, m0, n0, lds, acc);
  int t = threadIdx.x, lane = t & 63, wv = t >> 6;
  int g = lane >> 4, lr = lane & 15;
  int wrB = (wv >> 1) * 64, wcB = (wv & 1) * 64;
#pragma unroll
  for (int mi = 0; mi < 4; ++mi) {
    int rowbase = m0 + wrB + mi * 16 + g * 4;
    int b = rowbase >> 11, s = rowbase & 2047;
#pragma unroll
    for (int nj = 0; nj < 4; ++nj) {
      int col = n0 + wcB + nj * 16 + lr;
      float bv = bias[col];
      int sec = col >> 11;            // 0=Q 1=K 2=V
      int within = col & 2047;
      int h = within >> 7, d = within & 127;
      if (sec < 2) {
        float mult = (sec == 0) ? QSCALE : 1.0f;   // fold 1/sqrt(dh)*log2e into Q
        u16* dst = (sec == 0 ? Qb : Kb) + ((size_t)(b * NH_ + h) * S_ + s) * DH_ + d;
#pragma unroll
        for (int r = 0; r < 4; ++r) dst[(size_t)r * DH_] = f2bf((acc[mi][nj][r] + bv) * mult);
      } else {
        u16* dst = VTb + ((size_t)(b * NH_ + h) * DH_ + d) * S_ + s;  // V transposed
        ushort4 pk;
        pk.x = f2bf(acc[mi][nj][0] + bv); pk.y = f2bf(acc[mi][nj][1] + bv);
        pk.z = f2bf(acc[mi][nj][2] + bv); pk.w = f2bf(acc[mi][nj][3] + bv);
        *reinterpret_cast<ushort4*>(dst) = pk;
      }
    }
  }
}

// ---------------- GEMM2: AO @ Wproj + b -> fp32 out ----------------
__global__ __launch_bounds__(512, 1) void gemm_proj_kernel(
    const u16* __restrict__ A, const u16* __restrict__ BT, const float* __restrict__ bias,
    float* __restrict__ out) {
  __shared__ __attribute__((aligned(16))) u16 lds[49152];
  f32x4 acc[4][4] = {};
  int sw = swz_id();
  int n0 = (sw % gridDim.x) * 128, m0 = (sw / gridDim.x) * 256;
  gemm8_core<2048>(A, BT, m0, n0, lds, acc);
  int t = threadIdx.x, lane = t & 63, wv = t >> 6;
  int g = lane >> 4, lr = lane & 15;
  int wrB = (wv >> 1) * 64, wcB = (wv & 1) * 64;
#pragma unroll
  for (int mi = 0; mi < 4; ++mi) {
    int rowbase = m0 + wrB + mi * 16 + g * 4;
#pragma unroll
    for (int nj = 0; nj < 4; ++nj) {
      int col = n0 + wcB + nj * 16 + lr;
      float bv = bias[col];
      float* dst = out + (size_t)rowbase * D_ + col;
#pragma unroll
      for (int r = 0; r < 4; ++r) dst[(size_t)r * D_] = acc[mi][nj][r] + bv;
    }
  }
}

// ---------------- flash attention v4: 32 q-rows/wave (QBLK=128) -------------------
// Block = (b,h) x 128 Q rows, 4 waves x 32 rows (2 q-subtiles of 16). K/V LDS
// double-buffered. Swapped QK^T: each ak (K-frag) feeds BOTH subtiles' MFMAs, so
// the 16 K-frag + 16 V-frag ds_read_b128 per wave-tile now serve 2x the q-work
// (attn was LDS-read-throughput bound: 8 waves x 32 reads x ~15cy ~= measured
// 2900 cy/CU/iter). Softmax/repack per subtile; lane math identical (q offset 16).
__global__ __launch_bounds__(256, 2) void attn_kernel(
    const u16* __restrict__ Qb, const u16* __restrict__ Kb, const u16* __restrict__ VTb,
    const float* __restrict__ mask, u16* __restrict__ AO) {
  __shared__ __attribute__((aligned(16))) u16 Ks[2][64 * 128];
  __shared__ __attribute__((aligned(16))) u16 Vs[2][128 * 64];
  __shared__ float bias_lds[S_];

  int t = threadIdx.x, w = t >> 6, lane = t & 63;
  int g = lane >> 4, lr = lane & 15;
  int sw = swz_id();                 // group same-(b,h) blocks per XCD
  int qt = sw & 15, bh = sw >> 4;
  int b = bh >> 4;
  const u16* Qh = Qb + (size_t)bh * S_ * DH_;
  const u16* Kh = Kb + (size_t)bh * S_ * DH_;
  const u16* Vh = VTb + (size_t)bh * DH_ * S_;
  int q0 = qt * 128 + w * 32;

  for (int i = t; i < S_; i += 256)
    bias_lds[i] = (1.0f - mask[b * S_ + i]) * BIASF;

  // Q fragments for 2 q-subtiles (B-operand of swapped QK^T)
  bf16x8 bq[2][4];
#pragma unroll
  for (int qs = 0; qs < 2; ++qs)
#pragma unroll
    for (int kk = 0; kk < 4; ++kk)
      bq[qs][kk] = *reinterpret_cast<const bf16x8*>(
          Qh + (size_t)(q0 + qs * 16 + lr) * DH_ + kk * 32 + g * 8);

  f32x4 oacc[2][8] = {};
  float m_r[2] = {-1e30f, -1e30f}, l_r[2] = {0.f, 0.f};

  __syncthreads();   // bias_lds visible

#define STAGE_KV(buf, s0base)                                                    \
  {                                                                              \
    _Pragma("unroll")                                                            \
    for (int i = 0; i < 4; ++i) {                                                \
      int idx = i * 256 + t;                                                     \
      int row = idx >> 4, slot = idx & 15;                                       \
      GL2LDS(Kh + (size_t)((s0base) + row) * DH_ + ((slot ^ (row & 7)) * 8),     \
             &Ks[buf][idx * 8]);                                                 \
    }                                                                            \
    _Pragma("unroll")                                                            \
    for (int i = 0; i < 4; ++i) {                                                \
      int idx = i * 256 + t;                                                     \
      int row = idx >> 3, slot = idx & 7;                                        \
      GL2LDS(Vh + (size_t)row * S_ + (s0base) + ((slot ^ (row & 7)) * 8),        \
             &Vs[buf][idx * 8]);                                                 \
    }                                                                            \
  }

  STAGE_KV(0, 0);
  const int NT = S_ / 64;
  for (int it = 0; it < NT; ++it) {
    int cur = it & 1;
    if (it + 1 < NT) {
      STAGE_KV(cur ^ 1, (it + 1) * 64);
      asm volatile("s_waitcnt vmcnt(8)" ::: "memory");
    } else {
      asm volatile("s_waitcnt vmcnt(0)" ::: "memory");
    }
    __builtin_amdgcn_s_barrier();
    __builtin_amdgcn_sched_barrier(0);

    // QK^T swapped: each ak read feeds both q-subtiles
    f32x4 sacc[2][4] = {};
    __builtin_amdgcn_s_setprio(1);
#pragma unroll
    for (int kk = 0; kk < 4; ++kk) {
#pragma unroll
      for (int n = 0; n < 4; ++n) {
        int row = lr + 16 * n;
        bf16x8 ak = *reinterpret_cast<const bf16x8*>(
            &Ks[cur][row * 128 + ((((kk << 2) | g) ^ (row & 7)) * 8)]);
        sacc[0][n] = __builtin_amdgcn_mfma_f32_16x16x32_bf16(ak, bq[0][kk], sacc[0][n], 0, 0, 0);
        sacc[1][n] = __builtin_amdgcn_mfma_f32_16x16x32_bf16(ak, bq[1][kk], sacc[1][n], 0, 0, 0);
      }
    }
    __builtin_amdgcn_s_setprio(0);

    int s0 = it * 64;
    float4 bb[4];
#pragma unroll
    for (int n = 0; n < 4; ++n)
      bb[n] = *reinterpret_cast<const float4*>(&bias_lds[s0 + 16 * n + g * 4]);

    unsigned pku[2][4][2];
#pragma unroll
    for (int qs = 0; qs < 2; ++qs) {
      float sv[4][4];
      float mloc = -3e38f;
#pragma unroll
      for (int n = 0; n < 4; ++n) {
        sv[n][0] = sacc[qs][n][0] + bb[n].x; sv[n][1] = sacc[qs][n][1] + bb[n].y;
        sv[n][2] = sacc[qs][n][2] + bb[n].z; sv[n][3] = sacc[qs][n][3] + bb[n].w;
        mloc = fmaxf(mloc, fmaxf(fmaxf(sv[n][0], sv[n][1]), fmaxf(sv[n][2], sv[n][3])));
      }
      float mx = fmaxf(mloc, __shfl_xor(mloc, 16));
      mx = fmaxf(mx, __shfl_xor(mx, 32));

      if (__any(mx - m_r[qs] > 8.f)) {
        float mnew = fmaxf(m_r[qs], mx);
        float f = fast_exp2(m_r[qs] - mnew);
        m_r[qs] = mnew;
        l_r[qs] *= f;
#pragma unroll
        for (int no = 0; no < 8; ++no) oacc[qs][no] *= f;
      }

#pragma unroll
      for (int n = 0; n < 4; ++n) {
        float p0 = fast_exp2(sv[n][0] - m_r[qs]), p1 = fast_exp2(sv[n][1] - m_r[qs]);
        float p2 = fast_exp2(sv[n][2] - m_r[qs]), p3 = fast_exp2(sv[n][3] - m_r[qs]);
        l_r[qs] += (p0 + p1) + (p2 + p3);
        pku[qs][n][0] = cvtpk(p0, p1);
        pku[qs][n][1] = cvtpk(p2, p3);
      }
    }

    // PV swapped: each av read feeds both subtiles' MFMAs
    int srcA = ((g & 1) << 5) + lr;
    int srcB = srcA + 16;
    bool hi = (g >> 1) != 0;
#pragma unroll
    for (int kk2 = 0; kk2 < 2; ++kk2) {
      union { uint4 u; bf16x8 v; } pa[2];
#pragma unroll
      for (int qs = 0; qs < 2; ++qs) {
        unsigned a0 = __shfl(pku[qs][2 * kk2][0], srcA), a1 = __shfl(pku[qs][2 * kk2 + 1][0], srcA);
        unsigned b0 = __shfl(pku[qs][2 * kk2][1], srcA), b1 = __shfl(pku[qs][2 * kk2 + 1][1], srcA);
        unsigned c0 = __shfl(pku[qs][2 * kk2][0], srcB), c1 = __shfl(pku[qs][2 * kk2 + 1][0], srcB);
        unsigned d0 = __shfl(pku[qs][2 * kk2][1], srcB), d1 = __shfl(pku[qs][2 * kk2 + 1][1], srcB);
        pa[qs].u.x = hi ? a1 : a0; pa[qs].u.y = hi ? b1 : b0;
        pa[qs].u.z = hi ? c1 : c0; pa[qs].u.w = hi ? d1 : d0;
      }
      __builtin_amdgcn_s_setprio(1);
#pragma unroll
      for (int no = 0; no < 8; ++no) {
        int d = lr + 16 * no;
        bf16x8 av = *reinterpret_cast<const bf16x8*>(
            &Vs[cur][d * 64 + ((((kk2 << 2) | g) ^ (d & 7)) * 8)]);
        oacc[0][no] = __builtin_amdgcn_mfma_f32_16x16x32_bf16(av, pa[0].v, oacc[0][no], 0, 0, 0);
        oacc[1][no] = __builtin_amdgcn_mfma_f32_16x16x32_bf16(av, pa[1].v, oacc[1][no], 0, 0, 0);
      }
      __builtin_amdgcn_s_setprio(0);
    }
    __builtin_amdgcn_sched_barrier(0);
    __builtin_amdgcn_s_barrier();
  }
#undef STAGE_KV

  int h = bh & 15;
#pragma unroll
  for (int qs = 0; qs < 2; ++qs) {
    float s = l_r[qs];
    s += __shfl_xor(s, 16);
    s += __shfl_xor(s, 32);
    float inv = 1.0f / s;
    int q = q0 + qs * 16 + lr;
    u16* dst = AO + ((size_t)(b * S_ + q)) * D_ + h * DH_ + g * 4;
#pragma unroll
    for (int no = 0; no < 8; ++no) {
      ushort4 pk4;
      pk4.x = f2bf(oacc[qs][no][0] * inv); pk4.y = f2bf(oacc[qs][no][1] * inv);
      pk4.z = f2bf(oacc[qs][no][2] * inv); pk4.w = f2bf(oacc[qs][no][3] * inv);
      *reinterpret_cast<ushort4*>(dst + 16 * no) = pk4;
    }
  }
}

extern "C" void kernel_launch(void* const* d_in, const int* in_sizes, int n_in,
                              void* d_out, int out_size, void* d_ws, size_t ws_size,
                              hipStream_t stream) {
  const float* h_in   = (const float*)d_in[0];
  const float* mask   = (const float*)d_in[1];
  const float* w_attn = (const float*)d_in[2];
  const float* b_attn = (const float*)d_in[3];
  const float* w_proj = (const float*)d_in[4];
  const float* b_proj = (const float*)d_in[5];
  float* out = (float*)d_out;

  char* ws = (char*)d_ws;
  u16* Hb  = (u16*)(ws);                       // 16 MiB: H bf16 [4096][2048]
  u16* W1T = (u16*)(ws + 16777216);            // 24 MiB: Wattn^T bf16 [6144][2048]
  u16* W2T = (u16*)(ws + 41943040);            //  8 MiB: Wproj^T bf16 [2048][2048]
  u16* Qb  = (u16*)(ws + 50331648);            // 16 MiB: Q (prescaled) [B][H][S][128]
  u16* Kb  = (u16*)(ws + 67108864);            // 16 MiB: K  [B][H][S][128]
  u16* VTb = (u16*)(ws + 83886080);            // 16 MiB: V^T [B][H][128][S]
  u16* AO  = Hb;  // reuse H region for attention output (H dead after gemm_qkv)

  cvt_kernel<<<2048, 256, 0, stream>>>(h_in, Hb, (B_ * S_ * D_) / 4);
  dim3 tb(32, 8);
  transpose_kernel<<<dim3(N3_ / 32, D_ / 32), tb, 0, stream>>>(w_attn, W1T, D_, N3_);
  transpose_kernel<<<dim3(D_ / 32, D_ / 32), tb, 0, stream>>>(w_proj, W2T, D_, D_);
  gemm_qkv_kernel<<<dim3(N3_ / 128, (B_ * S_) / 256), 512, 0, stream>>>(
      Hb, W1T, b_attn, Qb, Kb, VTb);
  attn_kernel<<<dim3(S_ / 128, B_ * NH_), 256, 0, stream>>>(Qb, Kb, VTb, mask, AO);
  gemm_proj_kernel<<<dim3(D_ / 128, (B_ * S_) / 256), 512, 0, stream>>>(AO, W2T, b_proj, out);
}

// Round 12
// 394.195 us; speedup vs baseline: 1.2397x; 1.0159x over previous
//
#include <hip/hip_runtime.h>
#include <stdint.h>

// Problem constants
#define B_   2
#define S_   2048
#define D_   2048
#define NH_  16
#define DH_  128
#define N3_  6144

typedef unsigned short u16;
typedef __bf16 bf16x8 __attribute__((ext_vector_type(8)));
typedef float  f32x4  __attribute__((ext_vector_type(4)));

#define QSCALE   (0.08838834764831845f * 1.4426950408889634f)  // 1/sqrt(128) * log2(e)
#define BIASF    (-10000.0f * 1.4426950408889634f)

__device__ __forceinline__ u16 f2bf(float f) {
  union { float f; unsigned u; } v; v.f = f;
  unsigned u = v.u;
  return (u16)((u + 0x7FFFu + ((u >> 16) & 1u)) >> 16);
}

__device__ __forceinline__ float fast_exp2(float x) {
  float r;
  asm("v_exp_f32 %0, %1" : "=v"(r) : "v"(x));
  return r;
}

__device__ __forceinline__ unsigned cvtpk(float lo, float hi) {
  unsigned r;
  asm("v_cvt_pk_bf16_f32 %0, %1, %2" : "=v"(r) : "v"(lo), "v"(hi));
  return r;
}

// async global->LDS, 16B per lane; LDS dest must be wave-uniform-base + lane*16
#define GL2LDS(gsrc, ldst)                                                              \
  __builtin_amdgcn_global_load_lds((const __attribute__((address_space(1))) void*)(gsrc), \
      (__attribute__((address_space(3))) void*)(ldst), 16, 0, 0)

// XCD-aware block swizzle: contiguous logical chunk per XCD. Requires total%8==0.
__device__ __forceinline__ int swz_id() {
  int id = blockIdx.y * gridDim.x + blockIdx.x;
  int cpx = (gridDim.x * gridDim.y) >> 3;
  return (id & 7) * cpx + (id >> 3);
}

// ---------------- fused prep: transpose W1, transpose W2, cvt H ------------------
// One kernel replaces cvt + 2 transposes (kernel-count 6 -> 4; each graph node
// carries ~10-15us overhead). Block id ranges: [0,12288) t1 tiles (192x64),
// [12288,16384) t2 tiles (64x64), [16384,18432) cvt grid-stride.
#define T1_BLOCKS 12288
#define T2_BLOCKS 4096
#define CVT_BLOCKS 2048

__global__ __launch_bounds__(256) void prep_kernel(
    const float* __restrict__ h_in, u16* __restrict__ Hb,
    const float* __restrict__ w1, u16* __restrict__ W1T,
    const float* __restrict__ w2, u16* __restrict__ W2T) {
  __shared__ float tile[32][33];
  int id = blockIdx.x;
  int t = threadIdx.x;
  if (id < T1_BLOCKS + T2_BLOCKS) {
    const float* in;
    u16* out;
    int K, N, bx, by;
    if (id < T1_BLOCKS) {
      in = w1; out = W1T; K = D_; N = N3_;
      bx = id % (N3_ / 32); by = id / (N3_ / 32);
    } else {
      int id2 = id - T1_BLOCKS;
      in = w2; out = W2T; K = D_; N = D_;
      bx = id2 % (D_ / 32); by = id2 / (D_ / 32);
    }
    int tx = t & 31, ty = t >> 5;
    int nx = bx * 32, ky = by * 32;
#pragma unroll
    for (int j = 0; j < 32; j += 8)
      tile[ty + j][tx] = in[(size_t)(ky + ty + j) * N + nx + tx];
    __syncthreads();
#pragma unroll
    for (int j = 0; j < 32; j += 8)
      out[(size_t)(nx + ty + j) * K + ky + tx] = f2bf(tile[tx][ty + j]);
  } else {
    int i = (id - T1_BLOCKS - T2_BLOCKS) * 256 + t;
    const int n4 = (B_ * S_ * D_) / 4;
    const int stride = CVT_BLOCKS * 256;
    for (; i < n4; i += stride) {
      float4 v = ((const float4*)h_in)[i];
      ushort4 o;
      o.x = f2bf(v.x); o.y = f2bf(v.y); o.z = f2bf(v.z); o.w = f2bf(v.w);
      ((ushort4*)Hb)[i] = o;
    }
  }
}

// ========== 8-phase deep-pipelined GEMM: BM=256 x BN=128, BK=64 (unchanged) ======
#define G8_AB(c, qm) (lds + (c) * 24576 + (qm) * 8192)
#define G8_BB(c)     (lds + (c) * 24576 + 16384)
#define VMCNT(n) asm volatile("s_waitcnt vmcnt(" #n ")" ::: "memory")
#define LGKM0                                            \
  do {                                                   \
    asm volatile("s_waitcnt lgkmcnt(0)" ::: "memory");   \
    __builtin_amdgcn_sched_barrier(0);                   \
  } while (0)
#define BAR __builtin_amdgcn_s_barrier()

template <int KD>
__device__ __forceinline__ void stage_ah(const u16* __restrict__ A, u16* lds,
                                         int k, int qm, int m0, int t) {
  int c = k & 1;
#pragma unroll
  for (int inst = 0; inst < 2; ++inst) {
    int idx = inst * 512 + t;
    int hr = idx >> 3, p = idx & 7, L = p ^ (hr & 7);
    int r = ((hr >> 5) << 6) + qm * 32 + (hr & 31);
    GL2LDS(A + (size_t)(m0 + r) * KD + k * 64 + L * 8,
           G8_AB(c, qm) + idx * 8);
  }
}

template <int KD>
__device__ __forceinline__ void stage_bh(const u16* __restrict__ BT, u16* lds,
                                         int k, int n0, int t) {
  int c = k & 1;
#pragma unroll
  for (int inst = 0; inst < 2; ++inst) {
    int idx = inst * 512 + t;
    int hn = idx >> 3, p = idx & 7, L = p ^ (hn & 7);
    GL2LDS(BT + (size_t)(n0 + hn) * KD + k * 64 + L * 8,
           G8_BB(c) + idx * 8);
  }
}

__device__ __forceinline__ void read_aq(const u16* lds, int c, int qm, int wr, int g,
                                        int lr, bf16x8 (&af)[2][2]) {
  const u16* base = G8_AB(c, qm);
#pragma unroll
  for (int i = 0; i < 2; ++i) {
    int hr = wr * 32 + i * 16 + lr;
#pragma unroll
    for (int kk = 0; kk < 2; ++kk) {
      int slot = ((kk << 2) | g) ^ (hr & 7);
      af[i][kk] = *reinterpret_cast<const bf16x8*>(base + hr * 64 + slot * 8);
    }
  }
}

__device__ __forceinline__ void read_b(const u16* lds, int c, int wc, int g, int lr,
                                       bf16x8 (&bf)[4][2]) {
  const u16* base = G8_BB(c);
#pragma unroll
  for (int nj = 0; nj < 4; ++nj) {
    int hn = wc * 64 + nj * 16 + lr;
#pragma unroll
    for (int kk = 0; kk < 2; ++kk) {
      int slot = ((kk << 2) | g) ^ (hn & 7);
      bf[nj][kk] = *reinterpret_cast<const bf16x8*>(base + hn * 64 + slot * 8);
    }
  }
}

template <int QM>
__device__ __forceinline__ void mfma_q(const bf16x8 (&af)[2][2], const bf16x8 (&bf)[4][2],
                                       f32x4 (&acc)[4][4]) {
  __builtin_amdgcn_s_setprio(1);
#pragma unroll
  for (int i = 0; i < 2; ++i)
#pragma unroll
    for (int nj = 0; nj < 4; ++nj)
#pragma unroll
      for (int kk = 0; kk < 2; ++kk)
        acc[QM * 2 + i][nj] = __builtin_amdgcn_mfma_f32_16x16x32_bf16(
            af[i][kk], bf[nj][kk], acc[QM * 2 + i][nj], 0, 0, 0);
  __builtin_amdgcn_s_setprio(0);
}

template <int KD>
__device__ __forceinline__ void gemm8_core(const u16* __restrict__ A,
                                           const u16* __restrict__ BT,
                                           int m0, int n0, u16* lds, f32x4 (&acc)[4][4]) {
  const int NT = KD / 64;   // 32
  const int NC = NT / 2;    // 16
  int t = threadIdx.x, wv = t >> 6, lane = t & 63;
  int g = lane >> 4, lr = lane & 15;
  int wr = wv >> 1, wc = wv & 1;
  bf16x8 af[2][2], bf[4][2];

  stage_ah<KD>(A, lds, 0, 0, m0, t);
  stage_ah<KD>(A, lds, 0, 1, m0, t);
  stage_bh<KD>(BT, lds, 0, n0, t);
  stage_ah<KD>(A, lds, 1, 0, m0, t);
  stage_ah<KD>(A, lds, 1, 1, m0, t);
  stage_bh<KD>(BT, lds, 1, n0, t);
  VMCNT(0);
  BAR;

  for (int j = 0; j + 1 < NC; ++j) {
    read_aq(lds, 0, 0, wr, g, lr, af);
    read_b(lds, 0, wc, g, lr, bf);
    if (j >= 1) stage_ah<KD>(A, lds, 2 * j + 1, 1, m0, t);
    VMCNT(6); BAR; LGKM0;
    mfma_q<0>(af, bf, acc);
    BAR;
    read_aq(lds, 0, 1, wr, g, lr, af);
    stage_ah<KD>(A, lds, 2 * j + 2, 0, m0, t);
    stage_bh<KD>(BT, lds, 2 * j + 2, n0, t);
    VMCNT(6); BAR; LGKM0;
    mfma_q<1>(af, bf, acc);
    BAR;
    read_aq(lds, 1, 0, wr, g, lr, af);
    read_b(lds, 1, wc, g, lr, bf);
    stage_ah<KD>(A, lds, 2 * j + 2, 1, m0, t);
    VMCNT(6); BAR; LGKM0;
    mfma_q<0>(af, bf, acc);
    BAR;
    read_aq(lds, 1, 1, wr, g, lr, af);
    if (2 * j + 3 < NT) {
      stage_ah<KD>(A, lds, 2 * j + 3, 0, m0, t);
      stage_bh<KD>(BT, lds, 2 * j + 3, n0, t);
    }
    VMCNT(6); BAR; LGKM0;
    mfma_q<1>(af, bf, acc);
    BAR;
  }

  stage_ah<KD>(A, lds, NT - 1, 1, m0, t);
  VMCNT(0);
  BAR;
  read_aq(lds, 0, 0, wr, g, lr, af);
  read_b(lds, 0, wc, g, lr, bf);
  mfma_q<0>(af, bf, acc);
  read_aq(lds, 0, 1, wr, g, lr, af);
  mfma_q<1>(af, bf, acc);
  read_aq(lds, 1, 0, wr, g, lr, af);
  read_b(lds, 1, wc, g, lr, bf);
  mfma_q<0>(af, bf, acc);
  read_aq(lds, 1, 1, wr, g, lr, af);
  mfma_q<1>(af, bf, acc);
}

// ---------------- GEMM1: H @ Wattn + b -> scatter Q (prescaled), K, V^T ----------------
__global__ __launch_bounds__(512, 1) void gemm_qkv_kernel(
    const u16* __restrict__ A, const u16* __restrict__ BT, const float* __restrict__ bias,
    u16* __restrict__ Qb, u16* __restrict__ Kb, u16* __restrict__ VTb) {
  __shared__ __attribute__((aligned(16))) u16 lds[49152];
  f32x4 acc[4][4] = {};
  int sw = swz_id();
  int n0 = (sw % gridDim.x) * 128, m0 = (sw / gridDim.x) * 256;
  gemm8_core<2048>(A, BT, m0, n0, lds, acc);
  int t = threadIdx.x, lane = t & 63, wv = t >> 6;
  int g = lane >> 4, lr = lane & 15;
  int wrB = (wv >> 1) * 64, wcB = (wv & 1) * 64;
#pragma unroll
  for (int mi = 0; mi < 4; ++mi) {
    int rowbase = m0 + wrB + mi * 16 + g * 4;
    int b = rowbase >> 11, s = rowbase & 2047;
#pragma unroll
    for (int nj = 0; nj < 4; ++nj) {
      int col = n0 + wcB + nj * 16 + lr;
      float bv = bias[col];
      int sec = col >> 11;            // 0=Q 1=K 2=V
      int within = col & 2047;
      int h = within >> 7, d = within & 127;
      if (sec < 2) {
        float mult = (sec == 0) ? QSCALE : 1.0f;   // fold 1/sqrt(dh)*log2e into Q
        u16* dst = (sec == 0 ? Qb : Kb) + ((size_t)(b * NH_ + h) * S_ + s) * DH_ + d;
#pragma unroll
        for (int r = 0; r < 4; ++r) dst[(size_t)r * DH_] = f2bf((acc[mi][nj][r] + bv) * mult);
      } else {
        u16* dst = VTb + ((size_t)(b * NH_ + h) * DH_ + d) * S_ + s;  // V transposed
        ushort4 pk;
        pk.x = f2bf(acc[mi][nj][0] + bv); pk.y = f2bf(acc[mi][nj][1] + bv);
        pk.z = f2bf(acc[mi][nj][2] + bv); pk.w = f2bf(acc[mi][nj][3] + bv);
        *reinterpret_cast<ushort4*>(dst) = pk;
      }
    }
  }
}

// ---------------- GEMM2: AO @ Wproj + b -> fp32 out ----------------
__global__ __launch_bounds__(512, 1) void gemm_proj_kernel(
    const u16* __restrict__ A, const u16* __restrict__ BT, const float* __restrict__ bias,
    float* __restrict__ out) {
  __shared__ __attribute__((aligned(16))) u16 lds[49152];
  f32x4 acc[4][4] = {};
  int sw = swz_id();
  int n0 = (sw % gridDim.x) * 128, m0 = (sw / gridDim.x) * 256;
  gemm8_core<2048>(A, BT, m0, n0, lds, acc);
  int t = threadIdx.x, lane = t & 63, wv = t >> 6;
  int g = lane >> 4, lr = lane & 15;
  int wrB = (wv >> 1) * 64, wcB = (wv & 1) * 64;
#pragma unroll
  for (int mi = 0; mi < 4; ++mi) {
    int rowbase = m0 + wrB + mi * 16 + g * 4;
#pragma unroll
    for (int nj = 0; nj < 4; ++nj) {
      int col = n0 + wcB + nj * 16 + lr;
      float bv = bias[col];
      float* dst = out + (size_t)rowbase * D_ + col;
#pragma unroll
      for (int r = 0; r < 4; ++r) dst[(size_t)r * D_] = acc[mi][nj][r] + bv;
    }
  }
}

// ---------------- flash attention v4: 32 q-rows/wave (QBLK=128, unchanged) --------
__global__ __launch_bounds__(256, 2) void attn_kernel(
    const u16* __restrict__ Qb, const u16* __restrict__ Kb, const u16* __restrict__ VTb,
    const float* __restrict__ mask, u16* __restrict__ AO) {
  __shared__ __attribute__((aligned(16))) u16 Ks[2][64 * 128];
  __shared__ __attribute__((aligned(16))) u16 Vs[2][128 * 64];
  __shared__ float bias_lds[S_];

  int t = threadIdx.x, w = t >> 6, lane = t & 63;
  int g = lane >> 4, lr = lane & 15;
  int sw = swz_id();                 // group same-(b,h) blocks per XCD
  int qt = sw & 15, bh = sw >> 4;
  int b = bh >> 4;
  const u16* Qh = Qb + (size_t)bh * S_ * DH_;
  const u16* Kh = Kb + (size_t)bh * S_ * DH_;
  const u16* Vh = VTb + (size_t)bh * DH_ * S_;
  int q0 = qt * 128 + w * 32;

  for (int i = t; i < S_; i += 256)
    bias_lds[i] = (1.0f - mask[b * S_ + i]) * BIASF;

  bf16x8 bq[2][4];
#pragma unroll
  for (int qs = 0; qs < 2; ++qs)
#pragma unroll
    for (int kk = 0; kk < 4; ++kk)
      bq[qs][kk] = *reinterpret_cast<const bf16x8*>(
          Qh + (size_t)(q0 + qs * 16 + lr) * DH_ + kk * 32 + g * 8);

  f32x4 oacc[2][8] = {};
  float m_r[2] = {-1e30f, -1e30f}, l_r[2] = {0.f, 0.f};

  __syncthreads();   // bias_lds visible

#define STAGE_KV(buf, s0base)                                                    \
  {                                                                              \
    _Pragma("unroll")                                                            \
    for (int i = 0; i < 4; ++i) {                                                \
      int idx = i * 256 + t;                                                     \
      int row = idx >> 4, slot = idx & 15;                                       \
      GL2LDS(Kh + (size_t)((s0base) + row) * DH_ + ((slot ^ (row & 7)) * 8),     \
             &Ks[buf][idx * 8]);                                                 \
    }                                                                            \
    _Pragma("unroll")                                                            \
    for (int i = 0; i < 4; ++i) {                                                \
      int idx = i * 256 + t;                                                     \
      int row = idx >> 3, slot = idx & 7;                                        \
      GL2LDS(Vh + (size_t)row * S_ + (s0base) + ((slot ^ (row & 7)) * 8),        \
             &Vs[buf][idx * 8]);                                                 \
    }                                                                            \
  }

  STAGE_KV(0, 0);
  const int NT = S_ / 64;
  for (int it = 0; it < NT; ++it) {
    int cur = it & 1;
    if (it + 1 < NT) {
      STAGE_KV(cur ^ 1, (it + 1) * 64);
      asm volatile("s_waitcnt vmcnt(8)" ::: "memory");
    } else {
      asm volatile("s_waitcnt vmcnt(0)" ::: "memory");
    }
    __builtin_amdgcn_s_barrier();
    __builtin_amdgcn_sched_barrier(0);

    f32x4 sacc[2][4] = {};
    __builtin_amdgcn_s_setprio(1);
#pragma unroll
    for (int kk = 0; kk < 4; ++kk) {
#pragma unroll
      for (int n = 0; n < 4; ++n) {
        int row = lr + 16 * n;
        bf16x8 ak = *reinterpret_cast<const bf16x8*>(
            &Ks[cur][row * 128 + ((((kk << 2) | g) ^ (row & 7)) * 8)]);
        sacc[0][n] = __builtin_amdgcn_mfma_f32_16x16x32_bf16(ak, bq[0][kk], sacc[0][n], 0, 0, 0);
        sacc[1][n] = __builtin_amdgcn_mfma_f32_16x16x32_bf16(ak, bq[1][kk], sacc[1][n], 0, 0, 0);
      }
    }
    __builtin_amdgcn_s_setprio(0);

    int s0 = it * 64;
    float4 bb[4];
#pragma unroll
    for (int n = 0; n < 4; ++n)
      bb[n] = *reinterpret_cast<const float4*>(&bias_lds[s0 + 16 * n + g * 4]);

    unsigned pku[2][4][2];
#pragma unroll
    for (int qs = 0; qs < 2; ++qs) {
      float sv[4][4];
      float mloc = -3e38f;
#pragma unroll
      for (int n = 0; n < 4; ++n) {
        sv[n][0] = sacc[qs][n][0] + bb[n].x; sv[n][1] = sacc[qs][n][1] + bb[n].y;
        sv[n][2] = sacc[qs][n][2] + bb[n].z; sv[n][3] = sacc[qs][n][3] + bb[n].w;
        mloc = fmaxf(mloc, fmaxf(fmaxf(sv[n][0], sv[n][1]), fmaxf(sv[n][2], sv[n][3])));
      }
      float mx = fmaxf(mloc, __shfl_xor(mloc, 16));
      mx = fmaxf(mx, __shfl_xor(mx, 32));

      if (__any(mx - m_r[qs] > 8.f)) {
        float mnew = fmaxf(m_r[qs], mx);
        float f = fast_exp2(m_r[qs] - mnew);
        m_r[qs] = mnew;
        l_r[qs] *= f;
#pragma unroll
        for (int no = 0; no < 8; ++no) oacc[qs][no] *= f;
      }

#pragma unroll
      for (int n = 0; n < 4; ++n) {
        float p0 = fast_exp2(sv[n][0] - m_r[qs]), p1 = fast_exp2(sv[n][1] - m_r[qs]);
        float p2 = fast_exp2(sv[n][2] - m_r[qs]), p3 = fast_exp2(sv[n][3] - m_r[qs]);
        l_r[qs] += (p0 + p1) + (p2 + p3);
        pku[qs][n][0] = cvtpk(p0, p1);
        pku[qs][n][1] = cvtpk(p2, p3);
      }
    }

    int srcA = ((g & 1) << 5) + lr;
    int srcB = srcA + 16;
    bool hi = (g >> 1) != 0;
#pragma unroll
    for (int kk2 = 0; kk2 < 2; ++kk2) {
      union { uint4 u; bf16x8 v; } pa[2];
#pragma unroll
      for (int qs = 0; qs < 2; ++qs) {
        unsigned a0 = __shfl(pku[qs][2 * kk2][0], srcA), a1 = __shfl(pku[qs][2 * kk2 + 1][0], srcA);
        unsigned b0 = __shfl(pku[qs][2 * kk2][1], srcA), b1 = __shfl(pku[qs][2 * kk2 + 1][1], srcA);
        unsigned c0 = __shfl(pku[qs][2 * kk2][0], srcB), c1 = __shfl(pku[qs][2 * kk2 + 1][0], srcB);
        unsigned d0 = __shfl(pku[qs][2 * kk2][1], srcB), d1 = __shfl(pku[qs][2 * kk2 + 1][1], srcB);
        pa[qs].u.x = hi ? a1 : a0; pa[qs].u.y = hi ? b1 : b0;
        pa[qs].u.z = hi ? c1 : c0; pa[qs].u.w = hi ? d1 : d0;
      }
      __builtin_amdgcn_s_setprio(1);
#pragma unroll
      for (int no = 0; no < 8; ++no) {
        int d = lr + 16 * no;
        bf16x8 av = *reinterpret_cast<const bf16x8*>(
            &Vs[cur][d * 64 + ((((kk2 << 2) | g) ^ (d & 7)) * 8)]);
        oacc[0][no] = __builtin_amdgcn_mfma_f32_16x16x32_bf16(av, pa[0].v, oacc[0][no], 0, 0, 0);
        oacc[1][no] = __builtin_amdgcn_mfma_f32_16x16x32_bf16(av, pa[1].v, oacc[1][no], 0, 0, 0);
      }
      __builtin_amdgcn_s_setprio(0);
    }
    __builtin_amdgcn_sched_barrier(0);
    __builtin_amdgcn_s_barrier();
  }
#undef STAGE_KV

  int h = bh & 15;
#pragma unroll
  for (int qs = 0; qs < 2; ++qs) {
    float s = l_r[qs];
    s += __shfl_xor(s, 16);
    s += __shfl_xor(s, 32);
    float inv = 1.0f / s;
    int q = q0 + qs * 16 + lr;
    u16* dst = AO + ((size_t)(b * S_ + q)) * D_ + h * DH_ + g * 4;
#pragma unroll
    for (int no = 0; no < 8; ++no) {
      ushort4 pk4;
      pk4.x = f2bf(oacc[qs][no][0] * inv); pk4.y = f2bf(oacc[qs][no][1] * inv);
      pk4.z = f2bf(oacc[qs][no][2] * inv); pk4.w = f2bf(oacc[qs][no][3] * inv);
      *reinterpret_cast<ushort4*>(dst + 16 * no) = pk4;
    }
  }
}

extern "C" void kernel_launch(void* const* d_in, const int* in_sizes, int n_in,
                              void* d_out, int out_size, void* d_ws, size_t ws_size,
                              hipStream_t stream) {
  const float* h_in   = (const float*)d_in[0];
  const float* mask   = (const float*)d_in[1];
  const float* w_attn = (const float*)d_in[2];
  const float* b_attn = (const float*)d_in[3];
  const float* w_proj = (const float*)d_in[4];
  const float* b_proj = (const float*)d_in[5];
  float* out = (float*)d_out;

  char* ws = (char*)d_ws;
  u16* Hb  = (u16*)(ws);                       // 16 MiB: H bf16 [4096][2048]
  u16* W1T = (u16*)(ws + 16777216);            // 24 MiB: Wattn^T bf16 [6144][2048]
  u16* W2T = (u16*)(ws + 41943040);            //  8 MiB: Wproj^T bf16 [2048][2048]
  u16* Qb  = (u16*)(ws + 50331648);            // 16 MiB: Q (prescaled) [B][H][S][128]
  u16* Kb  = (u16*)(ws + 67108864);            // 16 MiB: K  [B][H][S][128]
  u16* VTb = (u16*)(ws + 83886080);            // 16 MiB: V^T [B][H][128][S]
  u16* AO  = Hb;  // reuse H region for attention output (H dead after gemm_qkv)

  prep_kernel<<<T1_BLOCKS + T2_BLOCKS + CVT_BLOCKS, 256, 0, stream>>>(
      h_in, Hb, w_attn, W1T, w_proj, W2T);
  gemm_qkv_kernel<<<dim3(N3_ / 128, (B_ * S_) / 256), 512, 0, stream>>>(
      Hb, W1T, b_attn, Qb, Kb, VTb);
  attn_kernel<<<dim3(S_ / 128, B_ * NH_), 256, 0, stream>>>(Qb, Kb, VTb, mask, AO);
  gemm_proj_kernel<<<dim3(D_ / 128, (B_ * S_) / 256), 512, 0, stream>>>(AO, W2T, b_proj, out);
}